// Round 5
// baseline (1514.755 us; speedup 1.0000x reference)
//
#include <hip/hip_runtime.h>
#include <hip/hip_bf16.h>

// WaveNet forward on gfx950 — round 5 (r4 + counted-vmcnt K-loops, T4/T5).
// Split-bf16 (hi/lo, 3-plane) MFMA everywhere, 32x32x16 fragments.
//   gated: BM=256 BN=128, 8 waves, wave=64x64 via acc[2][2] f32x16.
//   res/in: BM=128 BN=128, 4 waves, wave=64x64.
//   K-loops: raw s_barrier + counted s_waitcnt vmcnt(N) so next-chunk
//   global_load_lds stays in flight across barriers (no vmcnt(0) drain).
//   skip path collapsed to per-layer column sums (asum) + tiny head.
// Fallback (ws too small): round-1 fp32 VALU path.

#define TBLEN 4096
#define PAD 256
#define TP (TBLEN + PAD)
#define KC 32

typedef __bf16 bf16_t;
typedef __bf16 bf16x4 __attribute__((ext_vector_type(4)));
typedef __bf16 bf16x8 __attribute__((ext_vector_type(8)));
typedef float f32x4 __attribute__((ext_vector_type(4)));
typedef float f32x16 __attribute__((ext_vector_type(16)));

__device__ __align__(16) __bf16 g_wi_dev[98304];   // w_in split+swizzled
__device__ float g_pooled[4096];                    // [b][256] pooled skip

__device__ __forceinline__ void gl_lds16(const void* g, void* l) {
    __builtin_amdgcn_global_load_lds(
        (const __attribute__((address_space(1))) unsigned int*)g,
        (__attribute__((address_space(3))) unsigned int*)l, 16, 0, 0);
}

// ---------------- weight prep: split + swizzle ----------------
__global__ __launch_bounds__(256) void prep_wg_kernel(
    const float* __restrict__ dw, bf16_t* __restrict__ wg)
{
    int idx = blockIdx.x * 256 + threadIdx.x;   // 3,145,728
    int e = idx & 7, ps = (idx >> 3) & 3, row = (idx >> 5) & 255;
    int lc = idx >> 13, c = lc % 24, layer = lc / 24;
    int s = ps ^ ((row >> 1) & 3);
    int k = c * 32 + s * 8 + e;
    int plane = k >> 8, kp = k & 255;
    int tap = kp >> 7, ch = kp & 127;
    float w = dw[(((size_t)layer * 256 + row) * 128 + ch) * 2 + tap];
    bf16_t hb = (bf16_t)w;
    wg[idx] = (plane < 2) ? hb : (bf16_t)(w - (float)hb);
}

__global__ __launch_bounds__(256) void prep_wr_kernel(
    const float* __restrict__ rw, bf16_t* __restrict__ wr)
{
    int idx = blockIdx.x * 256 + threadIdx.x;   // 737,280
    int e = idx & 7, ps = (idx >> 3) & 3, row = (idx >> 5) & 127;
    int lc = idx >> 12, c = lc % 12, layer = lc / 12;
    int s = ps ^ ((row >> 1) & 3);
    int k = c * 32 + s * 8 + e;
    int plane = k >> 7, ch = k & 127;
    float w = rw[((size_t)layer * 128 + row) * 128 + ch];
    bf16_t hb = (bf16_t)w;
    wr[idx] = (plane < 2) ? hb : (bf16_t)(w - (float)hb);
}

__global__ __launch_bounds__(256) void prep_wi_kernel(const float* __restrict__ wi)
{
    int idx = blockIdx.x * 256 + threadIdx.x;   // 98,304
    int e = idx & 7, ps = (idx >> 3) & 3, row = (idx >> 5) & 127;
    int c = idx >> 12;                          // 0..23
    int s = ps ^ ((row >> 1) & 3);
    int k = c * 32 + s * 8 + e;
    int plane = k >> 8, ch = k & 255;
    float w = wi[(size_t)row * 256 + ch];
    bf16_t hb = (bf16_t)w;
    g_wi_dev[idx] = (plane < 2) ? hb : (bf16_t)(w - (float)hb);
}

__global__ __launch_bounds__(256) void zero_pads_kernel(
    bf16_t* __restrict__ xth, bf16_t* __restrict__ xtl)
{
    int idx = blockIdx.x * 256 + threadIdx.x;   // 524,288
    int ch = idx & 127, tp = (idx >> 7) & 255, b = idx >> 15;
    size_t o = ((size_t)b * TP + tp) * 128 + ch;
    xth[o] = (bf16_t)0.0f;
    xtl[o] = (bf16_t)0.0f;
    if (idx < 4096) g_pooled[idx] = 0.0f;
}

// ---------------- input transpose: fp32 [ch][t] -> bf16 hi/lo [t][ch] ----------------
__global__ __launch_bounds__(256) void transpose_in(
    const float* __restrict__ input, bf16_t* __restrict__ th,
    bf16_t* __restrict__ tl, int b_off)
{
    __shared__ float Sl[64][65];
    const int tid = threadIdx.x;
    const int t0 = blockIdx.x * 64, ch0 = blockIdx.y * 64, bz = blockIdx.z;
    const int b = b_off + bz;
#pragma unroll
    for (int it = 0; it < 16; ++it) {
        int idx = it * 256 + tid;
        int t = idx & 63, ch = idx >> 6;
        Sl[ch][t] = input[((size_t)b * 256 + ch0 + ch) * 4096 + t0 + t];
    }
    __syncthreads();
#pragma unroll
    for (int it = 0; it < 16; ++it) {
        int idx = it * 256 + tid;
        int ch = idx & 63, t = idx >> 6;
        float v = Sl[ch][t];
        bf16_t hb = (bf16_t)v;
        size_t o = ((size_t)bz * 4096 + t0 + t) * 256 + ch0 + ch;
        th[o] = hb;
        tl[o] = (bf16_t)(v - (float)hb);
    }
}

// ---------------- gated dilated conv, 32x32x16 MFMA ----------------
__global__ __launch_bounds__(512) void gated_mfma(
    const bf16_t* __restrict__ xth, const bf16_t* __restrict__ xtl,
    const bf16_t* __restrict__ wg, const float* __restrict__ dbias,
    bf16_t* __restrict__ ath, bf16_t* __restrict__ atl,
    float* __restrict__ asum_l, int d)
{
    __shared__ __align__(16) char lds[65536]; // W dbuf 2x16K @0, X dbuf 2x8K @32768; epi: act hi@0 lo@32768
    const int tid = threadIdx.x;
    const int wave = tid >> 6, lane = tid & 63;
    const int l31 = lane & 31, h = lane >> 5;
    const int wm = wave & 3, wn = wave >> 2;
    const int t0 = blockIdx.x * 128;
    const int b = blockIdx.z;

    f32x16 acc[2][2];
#pragma unroll
    for (int m = 0; m < 2; ++m)
#pragma unroll
        for (int n = 0; n < 2; ++n) acc[m][n] = (f32x16)(0.0f);

    const int t_pos = tid >> 2;
    const int s_x = (tid & 3) ^ ((t_pos >> 1) & 3);
    const long browbase = (long)b * TP + PAD + t0 + t_pos;

    auto stage = [&](int c, int sl) {
        const char* wsrc = (const char*)wg + (size_t)c * 16384;
        char* wdst = lds + sl * 16384;
#pragma unroll
        for (int it = 0; it < 2; ++it) {
            int g = tid + 512 * it;
            gl_lds16(wsrc + g * 16, wdst + g * 16);
        }
        int plane = c >> 3;
        int tap = (c >> 2) & 1;
        int ch = ((c & 3) << 5) + (s_x << 3);
        const bf16_t* src = (plane == 1) ? xtl : xth;
        long gi = (browbase + (tap ? 0 : -(long)d)) * 128 + ch;
        gl_lds16(src + gi, lds + 32768 + sl * 8192 + tid * 16);
    };

    stage(0, 0);
    const int swz = (l31 >> 1) & 3;
    int aoff[2][2], boff[2][2];
#pragma unroll
    for (int m = 0; m < 2; ++m)
#pragma unroll
        for (int s2 = 0; s2 < 2; ++s2)
            aoff[m][s2] = ((m ? 128 + wm * 32 : wm * 32) + l31) * 64 +
                          (((s2 * 2 + h) ^ swz) << 4);
#pragma unroll
    for (int n = 0; n < 2; ++n)
#pragma unroll
        for (int s2 = 0; s2 < 2; ++s2)
            boff[n][s2] = (wn * 64 + n * 32 + l31) * 64 + (((s2 * 2 + h) ^ swz) << 4);

    for (int c = 0; c < 24; ++c) {
        // issue next-chunk loads, then wait ONLY for current chunk's 3 loads
        if (c < 23) {
            stage(c + 1, (c + 1) & 1);
            asm volatile("s_waitcnt vmcnt(3)" ::: "memory");
        } else {
            asm volatile("s_waitcnt vmcnt(0)" ::: "memory");
        }
        __builtin_amdgcn_s_barrier();    // all waves' chunk-c loads landed

        const char* wb = lds + (c & 1) * 16384;
        const char* xb = lds + 32768 + (c & 1) * 8192;
        bf16x8 a0s[2], a1s[2], b0s[2], b1s[2];
#pragma unroll
        for (int s2 = 0; s2 < 2; ++s2) {
            a0s[s2] = *(const bf16x8*)(wb + aoff[0][s2]);
            a1s[s2] = *(const bf16x8*)(wb + aoff[1][s2]);
            b0s[s2] = *(const bf16x8*)(xb + boff[0][s2]);
            b1s[s2] = *(const bf16x8*)(xb + boff[1][s2]);
        }
        __builtin_amdgcn_s_setprio(1);
#pragma unroll
        for (int s2 = 0; s2 < 2; ++s2) {
            acc[0][0] = __builtin_amdgcn_mfma_f32_32x32x16_bf16(a0s[s2], b0s[s2], acc[0][0], 0, 0, 0);
            acc[0][1] = __builtin_amdgcn_mfma_f32_32x32x16_bf16(a0s[s2], b1s[s2], acc[0][1], 0, 0, 0);
            acc[1][0] = __builtin_amdgcn_mfma_f32_32x32x16_bf16(a1s[s2], b0s[s2], acc[1][0], 0, 0, 0);
            acc[1][1] = __builtin_amdgcn_mfma_f32_32x32x16_bf16(a1s[s2], b1s[s2], acc[1][1], 0, 0, 0);
        }
        __builtin_amdgcn_s_setprio(0);
        __builtin_amdgcn_s_barrier();    // reads of slot c&1 retired -> safe to restage
    }
    __syncthreads();

    // epilogue: act = tanh(a1)*sigmoid(a2) in-lane; col-sums; swizzled LDS stage
    float psum[16];
#pragma unroll
    for (int u = 0; u < 16; ++u) psum[u] = 0.0f;

#pragma unroll
    for (int n = 0; n < 2; ++n) {
        int t = wn * 64 + n * 32 + l31;
        int sw = (t & 7) << 4;
#pragma unroll
        for (int rg = 0; rg < 4; ++rg) {
            int ch0 = wm * 32 + rg * 8 + 4 * h;
            bf16x4 hv, lv;
#pragma unroll
            for (int j = 0; j < 4; ++j) {
                int r = rg * 4 + j;
                float a1v = acc[0][n][r] + dbias[ch0 + j];
                float a2v = acc[1][n][r] + dbias[128 + ch0 + j];
                float a = tanhf(a1v) * (1.0f / (1.0f + expf(-a2v)));
                psum[rg * 4 + j] += a;
                bf16_t hb = (bf16_t)a;
                hv[j] = hb;
                lv[j] = (bf16_t)(a - (float)hb);
            }
            int byte = t * 256 + ch0 * 2;
            int phys = byte ^ sw;
            *(bf16x4*)(lds + phys) = hv;
            *(bf16x4*)(lds + 32768 + phys) = lv;
        }
    }

#pragma unroll
    for (int u = 0; u < 16; ++u) {
        float v = psum[u];
        v += __shfl_xor(v, 1);
        v += __shfl_xor(v, 2);
        v += __shfl_xor(v, 4);
        v += __shfl_xor(v, 8);
        v += __shfl_xor(v, 16);
        psum[u] = v;
    }
    if (l31 == 0) {
#pragma unroll
        for (int u = 0; u < 16; ++u) {
            int ch = wm * 32 + (u >> 2) * 8 + 4 * h + (u & 3);
            atomicAdd(asum_l + b * 128 + ch, psum[u]);
        }
    }
    __syncthreads();

    // coalesced copy-out
#pragma unroll
    for (int it = 0; it < 8; ++it) {
        int g = it * 512 + tid;
        int byte = g * 16;
        int plane = byte >> 15;
        int off15 = byte & 32767;
        int t = off15 >> 8, off = off15 & 255;
        int logoff = off ^ ((t & 7) << 4);
        size_t go = ((size_t)b * TBLEN + t0 + t) * 256 + logoff;
        bf16_t* dst = plane ? atl : ath;
        *(uint4*)((char*)dst + go) = *(const uint4*)(lds + byte);
    }
}

// ---------------- pointwise MFMA (residual conv & input conv) ----------------
// BM=128, BN=128, 4 waves, wave 64x64, acc[2][2] of 32x32.
// LDS: W dbuf 2x8192 @0, X dbuf 2x8192 @16384.
template<int NCH, bool USE_GWI>
__global__ __launch_bounds__(256) void pw_mfma(
    const bf16_t* __restrict__ sh, const bf16_t* __restrict__ sl,
    const bf16_t* __restrict__ wptr, const float* __restrict__ bias,
    bf16_t* __restrict__ xth, bf16_t* __restrict__ xtl,
    int accumulate, int b_off)
{
    constexpr int NCHUNK = 3 * NCH / 32;
    constexpr int SH_PL = NCH / 32;
    __shared__ __align__(16) char lds[32768];
    const int tid = threadIdx.x;
    const int wave = tid >> 6, lane = tid & 63;
    const int l31 = lane & 31, h = lane >> 5;
    const int wm = wave & 1, wn = wave >> 1;
    const int t0 = blockIdx.x * 128;
    const int bz = blockIdx.z;

    const bf16_t* w = USE_GWI ? (const bf16_t*)g_wi_dev : wptr;

    f32x16 acc[2][2];
#pragma unroll
    for (int m = 0; m < 2; ++m)
#pragma unroll
        for (int n = 0; n < 2; ++n) acc[m][n] = (f32x16)(0.0f);

    auto stage = [&](int c, int sl_) {
        const char* wsrc = (const char*)w + (size_t)c * 8192;
        char* wdst = lds + sl_ * 8192;
#pragma unroll
        for (int it = 0; it < 2; ++it) {
            int g = tid + 256 * it;
            gl_lds16(wsrc + g * 16, wdst + g * 16);
        }
        int plane = c / SH_PL;
        int chb = (c % SH_PL) * 32;
        const bf16_t* src = (plane == 1) ? sl : sh;
#pragma unroll
        for (int it = 0; it < 2; ++it) {
            int row = (tid >> 2) + it * 64;
            int ps = tid & 3;
            int s_x = ps ^ ((row >> 1) & 3);
            size_t gi = ((size_t)bz * 4096 + t0 + row) * NCH + chb + s_x * 8;
            gl_lds16(src + gi, lds + 16384 + sl_ * 8192 + (row * 4 + ps) * 16);
        }
    };

    stage(0, 0);
    const int swz = (l31 >> 1) & 3;
    int aoff[2][2], boff[2][2];
#pragma unroll
    for (int m = 0; m < 2; ++m)
#pragma unroll
        for (int s2 = 0; s2 < 2; ++s2)
            aoff[m][s2] = (wm * 64 + m * 32 + l31) * 64 + (((s2 * 2 + h) ^ swz) << 4);
#pragma unroll
    for (int n = 0; n < 2; ++n)
#pragma unroll
        for (int s2 = 0; s2 < 2; ++s2)
            boff[n][s2] = (wn * 64 + n * 32 + l31) * 64 + (((s2 * 2 + h) ^ swz) << 4);

    for (int c = 0; c < NCHUNK; ++c) {
        if (c < NCHUNK - 1) {
            stage(c + 1, (c + 1) & 1);
            asm volatile("s_waitcnt vmcnt(4)" ::: "memory");
        } else {
            asm volatile("s_waitcnt vmcnt(0)" ::: "memory");
        }
        __builtin_amdgcn_s_barrier();

        const char* wb = lds + (c & 1) * 8192;
        const char* xb = lds + 16384 + (c & 1) * 8192;
        bf16x8 a0s[2], a1s[2], b0s[2], b1s[2];
#pragma unroll
        for (int s2 = 0; s2 < 2; ++s2) {
            a0s[s2] = *(const bf16x8*)(wb + aoff[0][s2]);
            a1s[s2] = *(const bf16x8*)(wb + aoff[1][s2]);
            b0s[s2] = *(const bf16x8*)(xb + boff[0][s2]);
            b1s[s2] = *(const bf16x8*)(xb + boff[1][s2]);
        }
        __builtin_amdgcn_s_setprio(1);
#pragma unroll
        for (int s2 = 0; s2 < 2; ++s2) {
            acc[0][0] = __builtin_amdgcn_mfma_f32_32x32x16_bf16(a0s[s2], b0s[s2], acc[0][0], 0, 0, 0);
            acc[0][1] = __builtin_amdgcn_mfma_f32_32x32x16_bf16(a0s[s2], b1s[s2], acc[0][1], 0, 0, 0);
            acc[1][0] = __builtin_amdgcn_mfma_f32_32x32x16_bf16(a1s[s2], b0s[s2], acc[1][0], 0, 0, 0);
            acc[1][1] = __builtin_amdgcn_mfma_f32_32x32x16_bf16(a1s[s2], b1s[s2], acc[1][1], 0, 0, 0);
        }
        __builtin_amdgcn_s_setprio(0);
        __builtin_amdgcn_s_barrier();
    }

    // epilogue: v = acc + bias (+ old hi+lo); re-split; write xt [t][ch]
    const int b = b_off + bz;
#pragma unroll
    for (int n = 0; n < 2; ++n) {
        int t = wn * 64 + n * 32 + l31;
        size_t trow = ((size_t)b * TP + PAD + t0 + t) * 128;
#pragma unroll
        for (int m = 0; m < 2; ++m) {
#pragma unroll
            for (int rg = 0; rg < 4; ++rg) {
                int ch0 = wm * 64 + m * 32 + rg * 8 + 4 * h;
                bf16x4 nh, nl;
                bf16x4 oh, ol;
                if (accumulate) {
                    oh = *(const bf16x4*)(xth + trow + ch0);
                    ol = *(const bf16x4*)(xtl + trow + ch0);
                }
#pragma unroll
                for (int j = 0; j < 4; ++j) {
                    int r = rg * 4 + j;
                    float v = acc[m][n][r] + bias[ch0 + j];
                    if (accumulate) v += (float)oh[j] + (float)ol[j];
                    bf16_t hb = (bf16_t)v;
                    nh[j] = hb;
                    nl[j] = (bf16_t)(v - (float)hb);
                }
                *(bf16x4*)(xth + trow + ch0) = nh;
                *(bf16x4*)(xtl + trow + ch0) = nl;
            }
        }
    }
}

// ---------------- output head ----------------
__global__ __launch_bounds__(256) void skip_partial(
    const float* __restrict__ asum, const float* __restrict__ skip_w)
{
    const int i = blockIdx.x >> 4, b = blockIdx.x & 15, s = threadIdx.x;
    const float* sw = skip_w + ((size_t)i * 256 + s) * 128;
    const float* as = asum + i * 2048 + b * 128;
    float t = 0.0f;
#pragma unroll 8
    for (int r = 0; r < 128; ++r) t = fmaf(sw[r], as[r], t);
    atomicAdd(&g_pooled[b * 256 + s], t);
}

__global__ __launch_bounds__(256) void head_kernel(
    const float* __restrict__ skip_b, const float* __restrict__ w_out,
    const float* __restrict__ lin_w, const float* __restrict__ lin_b,
    float* __restrict__ out)
{
    const int b = blockIdx.x;
    const int s = threadIdx.x;
    float sb = 0.0f;
#pragma unroll
    for (int i = 0; i < 16; ++i) sb += skip_b[i * 256 + s];
    __shared__ float pl[256];
    pl[s] = g_pooled[b * 256 + s] * (1.0f / 4096.0f) + sb;
    __syncthreads();
    __shared__ float o1[12];
    if (s < 12) {
        float v = 0.0f;
        for (int q = 0; q < 256; ++q) v = fmaf(w_out[s * 256 + q], pl[q], v);
        o1[s] = v;
    }
    __syncthreads();
    if (s < 12) {
        float v = lin_b[s];
#pragma unroll
        for (int m = 0; m < 12; ++m) v = fmaf(lin_w[s * 12 + m], o1[m], v);
        out[b * 12 + s] = v;
    }
}

// ================= fallback fp32 path (round-1, proven) =================
__global__ __launch_bounds__(256) void pw_conv_kernel(
    const float* __restrict__ src, const float* __restrict__ W,
    const float* __restrict__ bias, float* __restrict__ dst,
    int K, int accumulate)
{
    __shared__ float Wl[KC][68];
    __shared__ float Sl[KC][68];
    const int tid = threadIdx.x;
    const int t0 = blockIdx.x * 64;
    const int row0 = blockIdx.y * 64;
    const int b = blockIdx.z;
    const int i4 = (tid >> 4) * 4;
    const int j4 = (tid & 15) * 4;
    float acc[4][4];
#pragma unroll
    for (int r = 0; r < 4; ++r) {
        float bv = bias[row0 + i4 + r];
#pragma unroll
        for (int c = 0; c < 4; ++c) acc[r][c] = bv;
    }
    const float* sb = src + (size_t)b * K * 4096;
    for (int k0 = 0; k0 < K; k0 += KC) {
        __syncthreads();
#pragma unroll
        for (int it = 0; it < 8; ++it) {
            int idx = it * 256 + tid;
            int kk = idx & 31, oo = idx >> 5;
            Wl[kk][oo] = W[(size_t)(row0 + oo) * K + (k0 + kk)];
        }
#pragma unroll
        for (int it = 0; it < 8; ++it) {
            int idx = it * 256 + tid;
            int t = idx & 63, kk = idx >> 6;
            Sl[kk][t] = sb[(size_t)(k0 + kk) * 4096 + t0 + t];
        }
        __syncthreads();
#pragma unroll
        for (int kk = 0; kk < KC; ++kk) {
            float4 wv = *(const float4*)&Wl[kk][i4];
            float4 sv = *(const float4*)&Sl[kk][j4];
            float wr_[4] = {wv.x, wv.y, wv.z, wv.w};
            float sc[4] = {sv.x, sv.y, sv.z, sv.w};
#pragma unroll
            for (int r = 0; r < 4; ++r)
#pragma unroll
                for (int c = 0; c < 4; ++c)
                    acc[r][c] = fmaf(wr_[r], sc[c], acc[r][c]);
        }
    }
    float* db = dst + (size_t)b * 128 * 4096;
#pragma unroll
    for (int r = 0; r < 4; ++r) {
        float* p = db + (size_t)(row0 + i4 + r) * 4096 + t0 + j4;
        float4 v;
        if (accumulate) {
            float4 old = *(const float4*)p;
            v.x = acc[r][0] + old.x; v.y = acc[r][1] + old.y;
            v.z = acc[r][2] + old.z; v.w = acc[r][3] + old.w;
        } else {
            v.x = acc[r][0]; v.y = acc[r][1]; v.z = acc[r][2]; v.w = acc[r][3];
        }
        *(float4*)p = v;
    }
}

__global__ __launch_bounds__(256) void gated_conv_kernel(
    const float* __restrict__ x, const float* __restrict__ Wd,
    const float* __restrict__ dbias, float* __restrict__ acts, int d)
{
    __shared__ float Wt0[KC][68], Wt1[KC][68], Ws0[KC][68], Ws1[KC][68];
    __shared__ float Sc[KC][68], Sp[KC][68];
    const int tid = threadIdx.x;
    const int t0 = blockIdx.x * 64;
    const int row0 = blockIdx.y * 64;
    const int b = blockIdx.z;
    const int i4 = (tid >> 4) * 4;
    const int j4 = (tid & 15) * 4;
    float a1[4][4], a2[4][4];
#pragma unroll
    for (int r = 0; r < 4; ++r) {
        float bt = dbias[row0 + i4 + r];
        float bs = dbias[128 + row0 + i4 + r];
#pragma unroll
        for (int c = 0; c < 4; ++c) { a1[r][c] = bt; a2[r][c] = bs; }
    }
    const float* xb = x + (size_t)b * 128 * 4096;
    for (int k0 = 0; k0 < 128; k0 += KC) {
        __syncthreads();
#pragma unroll
        for (int it = 0; it < 8; ++it) {
            int idx = it * 256 + tid;
            int kk = idx & 31, oo = idx >> 5;
            float2 wt = *(const float2*)(Wd + ((size_t)(row0 + oo) * 128 + (k0 + kk)) * 2);
            float2 ws = *(const float2*)(Wd + ((size_t)(128 + row0 + oo) * 128 + (k0 + kk)) * 2);
            Wt0[kk][oo] = wt.x; Wt1[kk][oo] = wt.y;
            Ws0[kk][oo] = ws.x; Ws1[kk][oo] = ws.y;
        }
#pragma unroll
        for (int it = 0; it < 8; ++it) {
            int idx = it * 256 + tid;
            int t = idx & 63, kk = idx >> 6;
            Sc[kk][t] = xb[(size_t)(k0 + kk) * 4096 + t0 + t];
            int gt = t0 + t - d;
            Sp[kk][t] = (gt >= 0) ? xb[(size_t)(k0 + kk) * 4096 + gt] : 0.0f;
        }
        __syncthreads();
#pragma unroll
        for (int kk = 0; kk < KC; ++kk) {
            float4 xcv4 = *(const float4*)&Sc[kk][j4];
            float4 xpv4 = *(const float4*)&Sp[kk][j4];
            float4 wt0 = *(const float4*)&Wt0[kk][i4];
            float4 wt1 = *(const float4*)&Wt1[kk][i4];
            float4 ws0 = *(const float4*)&Ws0[kk][i4];
            float4 ws1 = *(const float4*)&Ws1[kk][i4];
            float xc[4] = {xcv4.x, xcv4.y, xcv4.z, xcv4.w};
            float xp[4] = {xpv4.x, xpv4.y, xpv4.z, xpv4.w};
            float t0r[4] = {wt0.x, wt0.y, wt0.z, wt0.w};
            float t1r[4] = {wt1.x, wt1.y, wt1.z, wt1.w};
            float s0r[4] = {ws0.x, ws0.y, ws0.z, ws0.w};
            float s1r[4] = {ws1.x, ws1.y, ws1.z, ws1.w};
#pragma unroll
            for (int r = 0; r < 4; ++r)
#pragma unroll
                for (int c = 0; c < 4; ++c) {
                    a1[r][c] = fmaf(t0r[r], xp[c], a1[r][c]);
                    a1[r][c] = fmaf(t1r[r], xc[c], a1[r][c]);
                    a2[r][c] = fmaf(s0r[r], xp[c], a2[r][c]);
                    a2[r][c] = fmaf(s1r[r], xc[c], a2[r][c]);
                }
        }
    }
    float* ab = acts + (size_t)b * 128 * 4096;
#pragma unroll
    for (int r = 0; r < 4; ++r) {
        float4 v;
#pragma unroll
        for (int c = 0; c < 4; ++c) {
            float th = tanhf(a1[r][c]);
            float sg = 1.0f / (1.0f + expf(-a2[r][c]));
            ((float*)&v)[c] = th * sg;
        }
        *(float4*)&ab[(size_t)(row0 + i4 + r) * 4096 + t0 + j4] = v;
    }
}

__global__ __launch_bounds__(256) void actsum_kernel(
    const float* __restrict__ acts, float* __restrict__ out)
{
    const int br = blockIdx.x;
    const float* p = acts + (size_t)br * 4096;
    float s = 0.0f;
#pragma unroll
    for (int c = 0; c < 16; ++c) s += p[c * 256 + threadIdx.x];
    __shared__ float red[256];
    red[threadIdx.x] = s;
    __syncthreads();
    for (int off = 128; off > 0; off >>= 1) {
        if (threadIdx.x < off) red[threadIdx.x] += red[threadIdx.x + off];
        __syncthreads();
    }
    if (threadIdx.x == 0) out[br] = red[0];
}

__global__ __launch_bounds__(256) void final_kernel(
    const float* __restrict__ actsum, const float* __restrict__ skip_w,
    const float* __restrict__ skip_b, const float* __restrict__ w_out,
    const float* __restrict__ lin_w, const float* __restrict__ lin_b,
    float* __restrict__ out)
{
    const int b = blockIdx.x;
    const int s = threadIdx.x;
    float acc = 0.0f;
    for (int i = 0; i < 16; ++i) {
        const float* sw = skip_w + ((size_t)i * 256 + s) * 128;
        const float* as = actsum + ((size_t)i * 16 + b) * 128;
        float t = 0.0f;
#pragma unroll 8
        for (int r = 0; r < 128; ++r) t = fmaf(sw[r], as[r], t);
        acc += t;
    }
    float sb = 0.0f;
    for (int i = 0; i < 16; ++i) sb += skip_b[i * 256 + s];
    __shared__ float pl[256];
    pl[s] = acc * (1.0f / 4096.0f) + sb;
    __syncthreads();
    __shared__ float o1[12];
    if (s < 12) {
        float v = 0.0f;
        for (int qq = 0; qq < 256; ++qq) v = fmaf(w_out[s * 256 + qq], pl[qq], v);
        o1[s] = v;
    }
    __syncthreads();
    if (s < 12) {
        float v = lin_b[s];
#pragma unroll
        for (int m = 0; m < 12; ++m) v = fmaf(lin_w[s * 12 + m], o1[m], v);
        out[b * 12 + s] = v;
    }
}

// =======================================================================
extern "C" void kernel_launch(void* const* d_in, const int* in_sizes, int n_in,
                              void* d_out, int out_size, void* d_ws, size_t ws_size,
                              hipStream_t stream)
{
    const float* input    = (const float*)d_in[0];
    const float* w_in     = (const float*)d_in[1];
    const float* b_in     = (const float*)d_in[2];
    const float* dilate_w = (const float*)d_in[3];
    const float* dilate_b = (const float*)d_in[4];
    const float* res_w    = (const float*)d_in[5];
    const float* res_b    = (const float*)d_in[6];
    const float* skip_w   = (const float*)d_in[7];
    const float* skip_b   = (const float*)d_in[8];
    const float* w_out    = (const float*)d_in[9];
    const float* lin_w    = (const float*)d_in[10];
    const float* lin_b    = (const float*)d_in[11];
    float* out = (float*)d_out;

    const size_t NEED = 77103104ULL;
    if (ws_size >= NEED) {
        char* base = (char*)d_ws;
        bf16_t* xt_hi = (bf16_t*)(base);                 // 17,825,792 B
        bf16_t* xt_lo = (bf16_t*)(base + 17825792);      // 17,825,792 B
        bf16_t* at_hi = (bf16_t*)(base + 35651584);      // 16,777,216 B
        bf16_t* at_lo = (bf16_t*)(base + 52428800);      // 16,777,216 B
        bf16_t* wg    = (bf16_t*)(base + 69206016);      //  6,291,456 B
        bf16_t* wr    = (bf16_t*)(base + 75497472);      //  1,474,560 B
        float*  asum  = (float*)(base + 76972032);       //    131,072 B

        hipMemsetAsync(asum, 0, 131072, stream);
        zero_pads_kernel<<<dim3(2048), dim3(256), 0, stream>>>(xt_hi, xt_lo);
        prep_wg_kernel<<<dim3(12288), dim3(256), 0, stream>>>(dilate_w, wg);
        prep_wr_kernel<<<dim3(2880), dim3(256), 0, stream>>>(res_w, wr);
        prep_wi_kernel<<<dim3(384), dim3(256), 0, stream>>>(w_in);

        // input conv in two 8-batch passes; acts buffers used as transpose scratch
        for (int pass = 0; pass < 2; ++pass) {
            transpose_in<<<dim3(64, 4, 8), dim3(256), 0, stream>>>(
                input, at_hi, at_lo, pass * 8);
            pw_mfma<256, true><<<dim3(32, 1, 8), dim3(256), 0, stream>>>(
                at_hi, at_lo, nullptr, b_in, xt_hi, xt_lo, 0, pass * 8);
        }

        for (int i = 0; i < 16; ++i) {
            int d = 1 << (i % 9);
            gated_mfma<<<dim3(32, 1, 16), dim3(512), 0, stream>>>(
                xt_hi, xt_lo, wg + (size_t)i * 196608, dilate_b + i * 256,
                at_hi, at_lo, asum + i * 2048, d);
            if (i < 15) {
                pw_mfma<128, false><<<dim3(32, 1, 16), dim3(256), 0, stream>>>(
                    at_hi, at_lo, wr + (size_t)i * 49152, res_b + i * 128,
                    xt_hi, xt_lo, 1, 0);
            }
        }
        skip_partial<<<dim3(256), dim3(256), 0, stream>>>(asum, skip_w);
        head_kernel<<<dim3(16), dim3(256), 0, stream>>>(
            skip_b, w_out, lin_w, lin_b, out);
    } else {
        // fallback: fp32 VALU path (round 1)
        float* ws   = (float*)d_ws;
        float* x    = ws;
        float* acts = ws + 8388608;
        float* asum = ws + 16777216;
        dim3 grid(64, 2, 16), blk(256, 1, 1);
        pw_conv_kernel<<<grid, blk, 0, stream>>>(input, w_in, b_in, x, 256, 0);
        for (int i = 0; i < 16; ++i) {
            int d = 1 << (i % 9);
            gated_conv_kernel<<<grid, blk, 0, stream>>>(
                x, dilate_w + (size_t)i * 256 * 128 * 2, dilate_b + i * 256, acts, d);
            actsum_kernel<<<dim3(2048), blk, 0, stream>>>(acts, asum + i * 2048);
            if (i < 15) {
                pw_conv_kernel<<<grid, blk, 0, stream>>>(
                    acts, res_w + (size_t)i * 128 * 128, res_b + i * 128, x, 128, 1);
            }
        }
        final_kernel<<<dim3(16), blk, 0, stream>>>(
            asum, skip_w, skip_b, w_out, lin_w, lin_b, out);
    }
}

// Round 6
// 1263.977 us; speedup vs baseline: 1.1984x; 1.1984x over previous
//
#include <hip/hip_runtime.h>
#include <hip/hip_bf16.h>

// WaveNet forward on gfx950 — round 6.
// Fused layer kernel: gated dilated conv (MFMA) + in-LDS acts + residual conv
// (MFMA) in ONE dispatch per layer. acts never touch global memory.
// Split-bf16 (hi/lo, 3-plane) arithmetic; fast exp2/rcp activations.
// x ping-pongs between two [b][4096][128] hi/lo buffer pairs (no causal pad:
// t<0 reads redirect per-lane to a shared zero page).
// Fallback (ws too small): round-1 fp32 VALU path.

#define KC 32

typedef __bf16 bf16_t;
typedef __bf16 bf16x4 __attribute__((ext_vector_type(4)));
typedef __bf16 bf16x8 __attribute__((ext_vector_type(8)));
typedef float f32x16 __attribute__((ext_vector_type(16)));

__device__ __align__(16) __bf16 g_wi_dev[98304];   // w_in split+swizzled
__device__ float g_pooled[4096];                    // [b][256] pooled skip

__device__ __forceinline__ void gl_lds16(const void* g, void* l) {
    __builtin_amdgcn_global_load_lds(
        (const __attribute__((address_space(1))) unsigned int*)g,
        (__attribute__((address_space(3))) unsigned int*)l, 16, 0, 0);
}

__device__ __forceinline__ float fast_sigmoid(float x) {
    float e = __builtin_amdgcn_exp2f(-1.4426950408889634f * x);
    return __builtin_amdgcn_rcpf(1.0f + e);
}
__device__ __forceinline__ float fast_tanh(float x) {
    float e = __builtin_amdgcn_exp2f(-2.8853900817779268f * x);
    return fmaf(2.0f, __builtin_amdgcn_rcpf(1.0f + e), -1.0f);
}

// ---------------- weight prep: split + swizzle ----------------
// chunk layout: [row][slot ps<4][e<8]; content slot s = ps ^ ((row>>1)&3);
// k'' = c*32 + s*8 + e.
__global__ __launch_bounds__(256) void prep_wg_kernel(
    const float* __restrict__ dw, bf16_t* __restrict__ wg)
{
    int idx = blockIdx.x * 256 + threadIdx.x;   // 3,145,728
    int e = idx & 7, ps = (idx >> 3) & 3, row = (idx >> 5) & 255;
    int lc = idx >> 13, c = lc % 24, layer = lc / 24;
    int s = ps ^ ((row >> 1) & 3);
    int k = c * 32 + s * 8 + e;
    int plane = k >> 8, kp = k & 255;
    int tap = kp >> 7, ch = kp & 127;
    float w = dw[(((size_t)layer * 256 + row) * 128 + ch) * 2 + tap];
    bf16_t hb = (bf16_t)w;
    wg[idx] = (plane < 2) ? hb : (bf16_t)(w - (float)hb);
}

__global__ __launch_bounds__(256) void prep_wr_kernel(
    const float* __restrict__ rw, bf16_t* __restrict__ wr)
{
    int idx = blockIdx.x * 256 + threadIdx.x;   // 737,280
    int e = idx & 7, ps = (idx >> 3) & 3, row = (idx >> 5) & 127;
    int lc = idx >> 12, c = lc % 12, layer = lc / 12;
    int s = ps ^ ((row >> 1) & 3);
    int k = c * 32 + s * 8 + e;
    int plane = k >> 7, ch = k & 127;
    float w = rw[((size_t)layer * 128 + row) * 128 + ch];
    bf16_t hb = (bf16_t)w;
    wr[idx] = (plane < 2) ? hb : (bf16_t)(w - (float)hb);
}

__global__ __launch_bounds__(256) void prep_wi_kernel(const float* __restrict__ wi)
{
    int idx = blockIdx.x * 256 + threadIdx.x;   // 98,304
    int e = idx & 7, ps = (idx >> 3) & 3, row = (idx >> 5) & 127;
    int c = idx >> 12;                          // 0..23
    int s = ps ^ ((row >> 1) & 3);
    int k = c * 32 + s * 8 + e;
    int plane = k >> 8, ch = k & 255;
    float w = wi[(size_t)row * 256 + ch];
    bf16_t hb = (bf16_t)w;
    g_wi_dev[idx] = (plane < 2) ? hb : (bf16_t)(w - (float)hb);
}

__global__ __launch_bounds__(256) void zero_misc_kernel(bf16_t* __restrict__ zeros)
{
    int idx = blockIdx.x * 256 + threadIdx.x;   // 32768
    zeros[idx] = (bf16_t)0.0f;
    if (idx < 4096) g_pooled[idx] = 0.0f;
}

// ---------------- input transpose: fp32 [ch][t] -> bf16 hi/lo [t][ch] ----------------
__global__ __launch_bounds__(256) void transpose_in(
    const float* __restrict__ input, bf16_t* __restrict__ th,
    bf16_t* __restrict__ tl, int b_off)
{
    __shared__ float Sl[64][65];
    const int tid = threadIdx.x;
    const int t0 = blockIdx.x * 64, ch0 = blockIdx.y * 64, bz = blockIdx.z;
    const int b = b_off + bz;
#pragma unroll
    for (int it = 0; it < 16; ++it) {
        int idx = it * 256 + tid;
        int t = idx & 63, ch = idx >> 6;
        Sl[ch][t] = input[((size_t)b * 256 + ch0 + ch) * 4096 + t0 + t];
    }
    __syncthreads();
#pragma unroll
    for (int it = 0; it < 16; ++it) {
        int idx = it * 256 + tid;
        int ch = idx & 63, t = idx >> 6;
        float v = Sl[ch][t];
        bf16_t hb = (bf16_t)v;
        size_t o = ((size_t)bz * 4096 + t0 + t) * 256 + ch0 + ch;
        th[o] = hb;
        tl[o] = (bf16_t)(v - (float)hb);
    }
}

// ---------------- fused layer: gated conv + acts + residual conv ----------------
// 512 threads (8 waves). LDS 80KB:
//   gated loop : W dbuf [0,32K), X dbuf [32K,48K)
//   epilogue   : acts hi [0,32K), acts lo [32K,64K), resW dbuf [64K,80K)
__global__ __launch_bounds__(512, 4) void fused_layer(
    const bf16_t* __restrict__ xc_hi, const bf16_t* __restrict__ xc_lo,
    bf16_t* __restrict__ xn_hi, bf16_t* __restrict__ xn_lo,
    const bf16_t* __restrict__ zeros,
    const bf16_t* __restrict__ wg_l, const float* __restrict__ dbias,
    const bf16_t* __restrict__ wr_l, const float* __restrict__ rbias,
    float* __restrict__ asum_l, int d, int skipres)
{
    __shared__ __align__(16) char lds[81920];
    const int tid = threadIdx.x;
    const int wave = tid >> 6, lane = tid & 63;
    const int l31 = lane & 31, h = lane >> 5;
    const int wm = wave & 3, wn = wave >> 2;
    const int t0 = blockIdx.x * 128;
    const int b = blockIdx.z;

    f32x16 acc[2][2];
#pragma unroll
    for (int m = 0; m < 2; ++m)
#pragma unroll
        for (int n = 0; n < 2; ++n) acc[m][n] = (f32x16)(0.0f);

    const int t_pos = tid >> 2;
    const int s_x = (tid & 3) ^ ((t_pos >> 1) & 3);
    const int chx = s_x << 3;

    auto stage_g = [&](int c, int sl) {
        const char* wsrc = (const char*)wg_l + (size_t)c * 16384;
        char* wdst = lds + sl * 16384;
        gl_lds16(wsrc + tid * 16, wdst + tid * 16);
        gl_lds16(wsrc + (tid + 512) * 16, wdst + (tid + 512) * 16);
        int plane = c >> 3;
        int tap = (c >> 2) & 1;
        int ch = ((c & 3) << 5) + chx;
        const bf16_t* src = (plane == 1) ? xc_lo : xc_hi;
        int tg = t0 + t_pos - (tap ? 0 : d);
        const bf16_t* sp = (tg >= 0) ? (src + ((size_t)b * 4096 + tg) * 128 + ch)
                                     : (zeros + ch);
        gl_lds16(sp, lds + 32768 + sl * 8192 + tid * 16);
    };

    stage_g(0, 0);
    const int swz = (l31 >> 1) & 3;
    int aoff[2][2], boff[2][2];
#pragma unroll
    for (int m = 0; m < 2; ++m)
#pragma unroll
        for (int s2 = 0; s2 < 2; ++s2)
            aoff[m][s2] = ((m ? 128 + wm * 32 : wm * 32) + l31) * 64 +
                          (((s2 * 2 + h) ^ swz) << 4);
#pragma unroll
    for (int n = 0; n < 2; ++n)
#pragma unroll
        for (int s2 = 0; s2 < 2; ++s2)
            boff[n][s2] = (wn * 64 + n * 32 + l31) * 64 + (((s2 * 2 + h) ^ swz) << 4);

    for (int c = 0; c < 24; ++c) {
        if (c < 23) {
            stage_g(c + 1, (c + 1) & 1);
            asm volatile("s_waitcnt vmcnt(3)" ::: "memory");
        } else {
            asm volatile("s_waitcnt vmcnt(0)" ::: "memory");
        }
        __builtin_amdgcn_s_barrier();

        const char* wb = lds + (c & 1) * 16384;
        const char* xb = lds + 32768 + (c & 1) * 8192;
        bf16x8 a0s[2], a1s[2], b0s[2], b1s[2];
#pragma unroll
        for (int s2 = 0; s2 < 2; ++s2) {
            a0s[s2] = *(const bf16x8*)(wb + aoff[0][s2]);
            a1s[s2] = *(const bf16x8*)(wb + aoff[1][s2]);
            b0s[s2] = *(const bf16x8*)(xb + boff[0][s2]);
            b1s[s2] = *(const bf16x8*)(xb + boff[1][s2]);
        }
        __builtin_amdgcn_s_setprio(1);
#pragma unroll
        for (int s2 = 0; s2 < 2; ++s2) {
            acc[0][0] = __builtin_amdgcn_mfma_f32_32x32x16_bf16(a0s[s2], b0s[s2], acc[0][0], 0, 0, 0);
            acc[0][1] = __builtin_amdgcn_mfma_f32_32x32x16_bf16(a0s[s2], b1s[s2], acc[0][1], 0, 0, 0);
            acc[1][0] = __builtin_amdgcn_mfma_f32_32x32x16_bf16(a1s[s2], b0s[s2], acc[1][0], 0, 0, 0);
            acc[1][1] = __builtin_amdgcn_mfma_f32_32x32x16_bf16(a1s[s2], b1s[s2], acc[1][1], 0, 0, 0);
        }
        __builtin_amdgcn_s_setprio(0);
        __builtin_amdgcn_s_barrier();
    }

    // ---- acts epilogue ----
    auto stage_rw = [&](int c, int sl) {
        gl_lds16((const char*)wr_l + (size_t)c * 8192 + tid * 16,
                 lds + 65536 + sl * 8192 + tid * 16);
    };
    if (!skipres) stage_rw(0, 0);   // HBM latency hides under activation VALU

    float psum[16];
#pragma unroll
    for (int u = 0; u < 16; ++u) psum[u] = 0.0f;

#pragma unroll
    for (int n = 0; n < 2; ++n) {
        int t = wn * 64 + n * 32 + l31;
        int sw = (t & 7) << 4;
#pragma unroll
        for (int rg = 0; rg < 4; ++rg) {
            int ch0 = wm * 32 + rg * 8 + 4 * h;
            bf16x4 hv, lv;
#pragma unroll
            for (int j = 0; j < 4; ++j) {
                int r = rg * 4 + j;
                float a1v = acc[0][n][r] + dbias[ch0 + j];
                float a2v = acc[1][n][r] + dbias[128 + ch0 + j];
                float a = fast_tanh(a1v) * fast_sigmoid(a2v);
                psum[rg * 4 + j] += a;
                bf16_t hb = (bf16_t)a;
                hv[j] = hb;
                lv[j] = (bf16_t)(a - (float)hb);
            }
            int low = (ch0 * 2) ^ sw;
            *(bf16x4*)(lds + t * 256 + low) = hv;
            *(bf16x4*)(lds + 32768 + t * 256 + low) = lv;
        }
    }

#pragma unroll
    for (int u = 0; u < 16; ++u) {
        float v = psum[u];
        v += __shfl_xor(v, 1);
        v += __shfl_xor(v, 2);
        v += __shfl_xor(v, 4);
        v += __shfl_xor(v, 8);
        v += __shfl_xor(v, 16);
        psum[u] = v;
    }
    if (l31 == 0) {
#pragma unroll
        for (int u = 0; u < 16; ++u) {
            int ch = wm * 32 + (u >> 2) * 8 + 4 * h + (u & 3);
            atomicAdd(asum_l + b * 128 + ch, psum[u]);
        }
    }
    if (skipres) return;

    asm volatile("s_waitcnt vmcnt(0) lgkmcnt(0)" ::: "memory");
    __builtin_amdgcn_s_barrier();   // acts visible to all waves; resW c0 landed

    // ---- residual K-loop: M=128(x ch) x N=128(t), K''=384, 12 chunks ----
    // wave tile 32ch x 64t: rows wm*32, cols wn*64.
    f32x16 accr[2];
    accr[0] = (f32x16)(0.0f);
    accr[1] = (f32x16)(0.0f);
    int tl_[2], mk_[2];
#pragma unroll
    for (int n = 0; n < 2; ++n) {
        tl_[n] = wn * 64 + n * 32 + l31;
        mk_[n] = (tl_[n] & 7) << 4;
    }

    for (int c = 0; c < 12; ++c) {
        if (c < 11) {
            stage_rw(c + 1, (c + 1) & 1);
            asm volatile("s_waitcnt vmcnt(1)" ::: "memory");
        } else {
            asm volatile("s_waitcnt vmcnt(0)" ::: "memory");
        }
        __builtin_amdgcn_s_barrier();

        const char* ab = lds + 65536 + (c & 1) * 8192;
        int p = c >> 2;
        int cb = (c & 3) << 6;
        const char* bb = lds + (p == 1 ? 32768 : 0);
        bf16x8 av[2], bv[2][2];
#pragma unroll
        for (int s2 = 0; s2 < 2; ++s2) {
            av[s2] = *(const bf16x8*)(ab + (wm * 32 + l31) * 64 +
                                      (((s2 * 2 + h) ^ swz) << 4));
#pragma unroll
            for (int n = 0; n < 2; ++n) {
                int low = (cb + ((s2 * 2 + h) << 4)) ^ mk_[n];
                bv[n][s2] = *(const bf16x8*)(bb + tl_[n] * 256 + low);
            }
        }
        __builtin_amdgcn_s_setprio(1);
#pragma unroll
        for (int s2 = 0; s2 < 2; ++s2) {
            accr[0] = __builtin_amdgcn_mfma_f32_32x32x16_bf16(av[s2], bv[0][s2], accr[0], 0, 0, 0);
            accr[1] = __builtin_amdgcn_mfma_f32_32x32x16_bf16(av[s2], bv[1][s2], accr[1], 0, 0, 0);
        }
        __builtin_amdgcn_s_setprio(0);
        __builtin_amdgcn_s_barrier();
    }

    // ---- residual epilogue: x_new = accr + rbias + x_old(hi+lo) ----
#pragma unroll
    for (int n = 0; n < 2; ++n) {
        int t = tl_[n];
        size_t trow = ((size_t)b * 4096 + t0 + t) * 128;
#pragma unroll
        for (int rg = 0; rg < 4; ++rg) {
            int ch0 = wm * 32 + rg * 8 + 4 * h;
            bf16x4 oh = *(const bf16x4*)(xc_hi + trow + ch0);
            bf16x4 ol = *(const bf16x4*)(xc_lo + trow + ch0);
            bf16x4 nh, nl;
#pragma unroll
            for (int j = 0; j < 4; ++j) {
                float v = accr[n][rg * 4 + j] + rbias[ch0 + j] +
                          (float)oh[j] + (float)ol[j];
                bf16_t hb = (bf16_t)v;
                nh[j] = hb;
                nl[j] = (bf16_t)(v - (float)hb);
            }
            *(bf16x4*)(xn_hi + trow + ch0) = nh;
            *(bf16x4*)(xn_lo + trow + ch0) = nl;
        }
    }
}

// ---------------- input pointwise MFMA (K=256, 3 planes) ----------------
// BM=128, BN=128, 4 waves, wave 64x64. Writes xt [b][4096][128] hi/lo.
__global__ __launch_bounds__(256) void pw_mfma_in(
    const bf16_t* __restrict__ sh, const bf16_t* __restrict__ sl,
    const float* __restrict__ bias,
    bf16_t* __restrict__ xth, bf16_t* __restrict__ xtl, int b_off)
{
    constexpr int NCHUNK = 24;
    __shared__ __align__(16) char lds[32768];
    const int tid = threadIdx.x;
    const int wave = tid >> 6, lane = tid & 63;
    const int l31 = lane & 31, h = lane >> 5;
    const int wm = wave & 1, wn = wave >> 1;
    const int t0 = blockIdx.x * 128;
    const int bz = blockIdx.z;
    const bf16_t* w = (const bf16_t*)g_wi_dev;

    f32x16 acc[2][2];
#pragma unroll
    for (int m = 0; m < 2; ++m)
#pragma unroll
        for (int n = 0; n < 2; ++n) acc[m][n] = (f32x16)(0.0f);

    auto stage = [&](int c, int sl_) {
        const char* wsrc = (const char*)w + (size_t)c * 8192;
        char* wdst = lds + sl_ * 8192;
#pragma unroll
        for (int it = 0; it < 2; ++it) {
            int g = tid + 256 * it;
            gl_lds16(wsrc + g * 16, wdst + g * 16);
        }
        int plane = c / 8;
        int chb = (c % 8) * 32;
        const bf16_t* src = (plane == 1) ? sl : sh;
#pragma unroll
        for (int it = 0; it < 2; ++it) {
            int row = (tid >> 2) + it * 64;
            int ps = tid & 3;
            int s_x = ps ^ ((row >> 1) & 3);
            size_t gi = ((size_t)bz * 4096 + t0 + row) * 256 + chb + s_x * 8;
            gl_lds16(src + gi, lds + 16384 + sl_ * 8192 + (row * 4 + ps) * 16);
        }
    };

    stage(0, 0);
    const int swz = (l31 >> 1) & 3;
    int aoff[2][2], boff[2][2];
#pragma unroll
    for (int m = 0; m < 2; ++m)
#pragma unroll
        for (int s2 = 0; s2 < 2; ++s2)
            aoff[m][s2] = (wm * 64 + m * 32 + l31) * 64 + (((s2 * 2 + h) ^ swz) << 4);
#pragma unroll
    for (int n = 0; n < 2; ++n)
#pragma unroll
        for (int s2 = 0; s2 < 2; ++s2)
            boff[n][s2] = (wn * 64 + n * 32 + l31) * 64 + (((s2 * 2 + h) ^ swz) << 4);

    for (int c = 0; c < NCHUNK; ++c) {
        if (c < NCHUNK - 1) {
            stage(c + 1, (c + 1) & 1);
            asm volatile("s_waitcnt vmcnt(4)" ::: "memory");
        } else {
            asm volatile("s_waitcnt vmcnt(0)" ::: "memory");
        }
        __builtin_amdgcn_s_barrier();

        const char* wb = lds + (c & 1) * 8192;
        const char* xb = lds + 16384 + (c & 1) * 8192;
#pragma unroll
        for (int s2 = 0; s2 < 2; ++s2) {
            bf16x8 a0 = *(const bf16x8*)(wb + aoff[0][s2]);
            bf16x8 a1 = *(const bf16x8*)(wb + aoff[1][s2]);
            bf16x8 b0 = *(const bf16x8*)(xb + boff[0][s2]);
            bf16x8 b1 = *(const bf16x8*)(xb + boff[1][s2]);
            acc[0][0] = __builtin_amdgcn_mfma_f32_32x32x16_bf16(a0, b0, acc[0][0], 0, 0, 0);
            acc[0][1] = __builtin_amdgcn_mfma_f32_32x32x16_bf16(a0, b1, acc[0][1], 0, 0, 0);
            acc[1][0] = __builtin_amdgcn_mfma_f32_32x32x16_bf16(a1, b0, acc[1][0], 0, 0, 0);
            acc[1][1] = __builtin_amdgcn_mfma_f32_32x32x16_bf16(a1, b1, acc[1][1], 0, 0, 0);
        }
        __builtin_amdgcn_s_barrier();
    }

    const int b = b_off + bz;
#pragma unroll
    for (int n = 0; n < 2; ++n) {
        int t = wn * 64 + n * 32 + l31;
        size_t trow = ((size_t)b * 4096 + t0 + t) * 128;
#pragma unroll
        for (int m = 0; m < 2; ++m) {
#pragma unroll
            for (int rg = 0; rg < 4; ++rg) {
                int ch0 = wm * 64 + m * 32 + rg * 8 + 4 * h;
                bf16x4 nh, nl;
#pragma unroll
                for (int j = 0; j < 4; ++j) {
                    float v = acc[m][n][rg * 4 + j] + bias[ch0 + j];
                    bf16_t hb = (bf16_t)v;
                    nh[j] = hb;
                    nl[j] = (bf16_t)(v - (float)hb);
                }
                *(bf16x4*)(xth + trow + ch0) = nh;
                *(bf16x4*)(xtl + trow + ch0) = nl;
            }
        }
    }
}

// ---------------- output head ----------------
__global__ __launch_bounds__(256) void skip_partial(
    const float* __restrict__ asum, const float* __restrict__ skip_w)
{
    const int i = blockIdx.x >> 4, b = blockIdx.x & 15, s = threadIdx.x;
    const float* sw = skip_w + ((size_t)i * 256 + s) * 128;
    const float* as = asum + i * 2048 + b * 128;
    float t = 0.0f;
#pragma unroll 8
    for (int r = 0; r < 128; ++r) t = fmaf(sw[r], as[r], t);
    atomicAdd(&g_pooled[b * 256 + s], t);
}

__global__ __launch_bounds__(256) void head_kernel(
    const float* __restrict__ skip_b, const float* __restrict__ w_out,
    const float* __restrict__ lin_w, const float* __restrict__ lin_b,
    float* __restrict__ out)
{
    const int b = blockIdx.x;
    const int s = threadIdx.x;
    float sb = 0.0f;
#pragma unroll
    for (int i = 0; i < 16; ++i) sb += skip_b[i * 256 + s];
    __shared__ float pl[256];
    pl[s] = g_pooled[b * 256 + s] * (1.0f / 4096.0f) + sb;
    __syncthreads();
    __shared__ float o1[12];
    if (s < 12) {
        float v = 0.0f;
        for (int q = 0; q < 256; ++q) v = fmaf(w_out[s * 256 + q], pl[q], v);
        o1[s] = v;
    }
    __syncthreads();
    if (s < 12) {
        float v = lin_b[s];
#pragma unroll
        for (int m = 0; m < 12; ++m) v = fmaf(lin_w[s * 12 + m], o1[m], v);
        out[b * 12 + s] = v;
    }
}

// ================= fallback fp32 path (round-1, proven) =================
__global__ __launch_bounds__(256) void pw_conv_kernel(
    const float* __restrict__ src, const float* __restrict__ W,
    const float* __restrict__ bias, float* __restrict__ dst,
    int K, int accumulate)
{
    __shared__ float Wl[KC][68];
    __shared__ float Sl[KC][68];
    const int tid = threadIdx.x;
    const int t0 = blockIdx.x * 64;
    const int row0 = blockIdx.y * 64;
    const int b = blockIdx.z;
    const int i4 = (tid >> 4) * 4;
    const int j4 = (tid & 15) * 4;
    float acc[4][4];
#pragma unroll
    for (int r = 0; r < 4; ++r) {
        float bv = bias[row0 + i4 + r];
#pragma unroll
        for (int c = 0; c < 4; ++c) acc[r][c] = bv;
    }
    const float* sb = src + (size_t)b * K * 4096;
    for (int k0 = 0; k0 < K; k0 += KC) {
        __syncthreads();
#pragma unroll
        for (int it = 0; it < 8; ++it) {
            int idx = it * 256 + tid;
            int kk = idx & 31, oo = idx >> 5;
            Wl[kk][oo] = W[(size_t)(row0 + oo) * K + (k0 + kk)];
        }
#pragma unroll
        for (int it = 0; it < 8; ++it) {
            int idx = it * 256 + tid;
            int t = idx & 63, kk = idx >> 6;
            Sl[kk][t] = sb[(size_t)(k0 + kk) * 4096 + t0 + t];
        }
        __syncthreads();
#pragma unroll
        for (int kk = 0; kk < KC; ++kk) {
            float4 wv = *(const float4*)&Wl[kk][i4];
            float4 sv = *(const float4*)&Sl[kk][j4];
            float wr_[4] = {wv.x, wv.y, wv.z, wv.w};
            float sc[4] = {sv.x, sv.y, sv.z, sv.w};
#pragma unroll
            for (int r = 0; r < 4; ++r)
#pragma unroll
                for (int c = 0; c < 4; ++c)
                    acc[r][c] = fmaf(wr_[r], sc[c], acc[r][c]);
        }
    }
    float* db = dst + (size_t)b * 128 * 4096;
#pragma unroll
    for (int r = 0; r < 4; ++r) {
        float* p = db + (size_t)(row0 + i4 + r) * 4096 + t0 + j4;
        float4 v;
        if (accumulate) {
            float4 old = *(const float4*)p;
            v.x = acc[r][0] + old.x; v.y = acc[r][1] + old.y;
            v.z = acc[r][2] + old.z; v.w = acc[r][3] + old.w;
        } else {
            v.x = acc[r][0]; v.y = acc[r][1]; v.z = acc[r][2]; v.w = acc[r][3];
        }
        *(float4*)p = v;
    }
}

__global__ __launch_bounds__(256) void gated_conv_kernel(
    const float* __restrict__ x, const float* __restrict__ Wd,
    const float* __restrict__ dbias, float* __restrict__ acts, int d)
{
    __shared__ float Wt0[KC][68], Wt1[KC][68], Ws0[KC][68], Ws1[KC][68];
    __shared__ float Sc[KC][68], Sp[KC][68];
    const int tid = threadIdx.x;
    const int t0 = blockIdx.x * 64;
    const int row0 = blockIdx.y * 64;
    const int b = blockIdx.z;
    const int i4 = (tid >> 4) * 4;
    const int j4 = (tid & 15) * 4;
    float a1[4][4], a2[4][4];
#pragma unroll
    for (int r = 0; r < 4; ++r) {
        float bt = dbias[row0 + i4 + r];
        float bs = dbias[128 + row0 + i4 + r];
#pragma unroll
        for (int c = 0; c < 4; ++c) { a1[r][c] = bt; a2[r][c] = bs; }
    }
    const float* xb = x + (size_t)b * 128 * 4096;
    for (int k0 = 0; k0 < 128; k0 += KC) {
        __syncthreads();
#pragma unroll
        for (int it = 0; it < 8; ++it) {
            int idx = it * 256 + tid;
            int kk = idx & 31, oo = idx >> 5;
            float2 wt = *(const float2*)(Wd + ((size_t)(row0 + oo) * 128 + (k0 + kk)) * 2);
            float2 ws = *(const float2*)(Wd + ((size_t)(128 + row0 + oo) * 128 + (k0 + kk)) * 2);
            Wt0[kk][oo] = wt.x; Wt1[kk][oo] = wt.y;
            Ws0[kk][oo] = ws.x; Ws1[kk][oo] = ws.y;
        }
#pragma unroll
        for (int it = 0; it < 8; ++it) {
            int idx = it * 256 + tid;
            int t = idx & 63, kk = idx >> 6;
            Sc[kk][t] = xb[(size_t)(k0 + kk) * 4096 + t0 + t];
            int gt = t0 + t - d;
            Sp[kk][t] = (gt >= 0) ? xb[(size_t)(k0 + kk) * 4096 + gt] : 0.0f;
        }
        __syncthreads();
#pragma unroll
        for (int kk = 0; kk < KC; ++kk) {
            float4 xcv4 = *(const float4*)&Sc[kk][j4];
            float4 xpv4 = *(const float4*)&Sp[kk][j4];
            float4 wt0 = *(const float4*)&Wt0[kk][i4];
            float4 wt1 = *(const float4*)&Wt1[kk][i4];
            float4 ws0 = *(const float4*)&Ws0[kk][i4];
            float4 ws1 = *(const float4*)&Ws1[kk][i4];
            float xc[4] = {xcv4.x, xcv4.y, xcv4.z, xcv4.w};
            float xp[4] = {xpv4.x, xpv4.y, xpv4.z, xpv4.w};
            float t0r[4] = {wt0.x, wt0.y, wt0.z, wt0.w};
            float t1r[4] = {wt1.x, wt1.y, wt1.z, wt1.w};
            float s0r[4] = {ws0.x, ws0.y, ws0.z, ws0.w};
            float s1r[4] = {ws1.x, ws1.y, ws1.z, ws1.w};
#pragma unroll
            for (int r = 0; r < 4; ++r)
#pragma unroll
                for (int c = 0; c < 4; ++c) {
                    a1[r][c] = fmaf(t0r[r], xp[c], a1[r][c]);
                    a1[r][c] = fmaf(t1r[r], xc[c], a1[r][c]);
                    a2[r][c] = fmaf(s0r[r], xp[c], a2[r][c]);
                    a2[r][c] = fmaf(s1r[r], xc[c], a2[r][c]);
                }
        }
    }
    float* ab = acts + (size_t)b * 128 * 4096;
#pragma unroll
    for (int r = 0; r < 4; ++r) {
        float4 v;
#pragma unroll
        for (int c = 0; c < 4; ++c) {
            float th = tanhf(a1[r][c]);
            float sg = 1.0f / (1.0f + expf(-a2[r][c]));
            ((float*)&v)[c] = th * sg;
        }
        *(float4*)&ab[(size_t)(row0 + i4 + r) * 4096 + t0 + j4] = v;
    }
}

__global__ __launch_bounds__(256) void actsum_kernel(
    const float* __restrict__ acts, float* __restrict__ out)
{
    const int br = blockIdx.x;
    const float* p = acts + (size_t)br * 4096;
    float s = 0.0f;
#pragma unroll
    for (int c = 0; c < 16; ++c) s += p[c * 256 + threadIdx.x];
    __shared__ float red[256];
    red[threadIdx.x] = s;
    __syncthreads();
    for (int off = 128; off > 0; off >>= 1) {
        if (threadIdx.x < off) red[threadIdx.x] += red[threadIdx.x + off];
        __syncthreads();
    }
    if (threadIdx.x == 0) out[br] = red[0];
}

__global__ __launch_bounds__(256) void final_kernel(
    const float* __restrict__ actsum, const float* __restrict__ skip_w,
    const float* __restrict__ skip_b, const float* __restrict__ w_out,
    const float* __restrict__ lin_w, const float* __restrict__ lin_b,
    float* __restrict__ out)
{
    const int b = blockIdx.x;
    const int s = threadIdx.x;
    float acc = 0.0f;
    for (int i = 0; i < 16; ++i) {
        const float* sw = skip_w + ((size_t)i * 256 + s) * 128;
        const float* as = actsum + ((size_t)i * 16 + b) * 128;
        float t = 0.0f;
#pragma unroll 8
        for (int r = 0; r < 128; ++r) t = fmaf(sw[r], as[r], t);
        acc += t;
    }
    float sb = 0.0f;
    for (int i = 0; i < 16; ++i) sb += skip_b[i * 256 + s];
    __shared__ float pl[256];
    pl[s] = acc * (1.0f / 4096.0f) + sb;
    __syncthreads();
    __shared__ float o1[12];
    if (s < 12) {
        float v = 0.0f;
        for (int qq = 0; qq < 256; ++qq) v = fmaf(w_out[s * 256 + qq], pl[qq], v);
        o1[s] = v;
    }
    __syncthreads();
    if (s < 12) {
        float v = lin_b[s];
#pragma unroll
        for (int m = 0; m < 12; ++m) v = fmaf(lin_w[s * 12 + m], o1[m], v);
        out[b * 12 + s] = v;
    }
}

// =======================================================================
extern "C" void kernel_launch(void* const* d_in, const int* in_sizes, int n_in,
                              void* d_out, int out_size, void* d_ws, size_t ws_size,
                              hipStream_t stream)
{
    const float* input    = (const float*)d_in[0];
    const float* w_in     = (const float*)d_in[1];
    const float* b_in     = (const float*)d_in[2];
    const float* dilate_w = (const float*)d_in[3];
    const float* dilate_b = (const float*)d_in[4];
    const float* res_w    = (const float*)d_in[5];
    const float* res_b    = (const float*)d_in[6];
    const float* skip_w   = (const float*)d_in[7];
    const float* skip_b   = (const float*)d_in[8];
    const float* w_out    = (const float*)d_in[9];
    const float* lin_w    = (const float*)d_in[10];
    const float* lin_b    = (const float*)d_in[11];
    float* out = (float*)d_out;

    const size_t NEED = 77103104ULL;
    if (ws_size >= NEED) {
        char* base = (char*)d_ws;
        bf16_t* xtA_hi = (bf16_t*)(base);                 // 16,777,216 B
        bf16_t* xtA_lo = (bf16_t*)(base + 16777216);      // 16,777,216 B
        bf16_t* xtB_hi = (bf16_t*)(base + 33554432);      // 16,777,216 B
        bf16_t* xtB_lo = (bf16_t*)(base + 50331648);      // 16,777,216 B
        bf16_t* wg     = (bf16_t*)(base + 67108864);      //  6,291,456 B
        bf16_t* wr     = (bf16_t*)(base + 73400320);      //  1,474,560 B
        float*  asum   = (float*)(base + 74874880);       //    131,072 B
        bf16_t* zeros  = (bf16_t*)(base + 75005952);      //     65,536 B

        hipMemsetAsync(asum, 0, 131072, stream);
        zero_misc_kernel<<<dim3(128), dim3(256), 0, stream>>>(zeros);
        prep_wg_kernel<<<dim3(12288), dim3(256), 0, stream>>>(dilate_w, wg);
        prep_wr_kernel<<<dim3(2880), dim3(256), 0, stream>>>(res_w, wr);
        prep_wi_kernel<<<dim3(384), dim3(256), 0, stream>>>(w_in);

        // input conv in two 8-batch passes; xtB buffers as transpose scratch
        for (int pass = 0; pass < 2; ++pass) {
            transpose_in<<<dim3(64, 4, 8), dim3(256), 0, stream>>>(
                input, xtB_hi, xtB_lo, pass * 8);
            pw_mfma_in<<<dim3(32, 1, 8), dim3(256), 0, stream>>>(
                xtB_hi, xtB_lo, b_in, xtA_hi, xtA_lo, pass * 8);
        }

        for (int i = 0; i < 16; ++i) {
            int d = 1 << (i % 9);
            const bf16_t* xc_hi = (i & 1) ? xtB_hi : xtA_hi;
            const bf16_t* xc_lo = (i & 1) ? xtB_lo : xtA_lo;
            bf16_t* xn_hi = (i & 1) ? xtA_hi : xtB_hi;
            bf16_t* xn_lo = (i & 1) ? xtA_lo : xtB_lo;
            int skipres = (i == 15) ? 1 : 0;
            fused_layer<<<dim3(32, 1, 16), dim3(512), 0, stream>>>(
                xc_hi, xc_lo, xn_hi, xn_lo, zeros,
                wg + (size_t)i * 196608, dilate_b + i * 256,
                wr + (size_t)(skipres ? 0 : i) * 49152,
                res_b + (skipres ? 0 : i) * 128,
                asum + i * 2048, d, skipres);
        }
        skip_partial<<<dim3(256), dim3(256), 0, stream>>>(asum, skip_w);
        head_kernel<<<dim3(16), dim3(256), 0, stream>>>(
            skip_b, w_out, lin_w, lin_b, out);
    } else {
        // fallback: fp32 VALU path (round 1)
        float* ws   = (float*)d_ws;
        float* x    = ws;
        float* acts = ws + 8388608;
        float* asum = ws + 16777216;
        dim3 grid(64, 2, 16), blk(256, 1, 1);
        pw_conv_kernel<<<grid, blk, 0, stream>>>(input, w_in, b_in, x, 256, 0);
        for (int i = 0; i < 16; ++i) {
            int d = 1 << (i % 9);
            gated_conv_kernel<<<grid, blk, 0, stream>>>(
                x, dilate_w + (size_t)i * 256 * 128 * 2, dilate_b + i * 256, acts, d);
            actsum_kernel<<<dim3(2048), blk, 0, stream>>>(acts, asum + i * 2048);
            if (i < 15) {
                pw_conv_kernel<<<grid, blk, 0, stream>>>(
                    acts, res_w + (size_t)i * 128 * 128, res_b + i * 128, x, 128, 1);
            }
        }
        final_kernel<<<dim3(16), blk, 0, stream>>>(
            asum, skip_w, skip_b, w_out, lin_w, lin_b, out);
    }
}

// Round 7
// 1248.506 us; speedup vs baseline: 1.2133x; 1.0124x over previous
//
#include <hip/hip_runtime.h>
#include <hip/hip_bf16.h>

// WaveNet forward on gfx950 — round 7 (r6 + depth-2 prefetch in gated K-loop).
// Fused layer kernel: gated dilated conv (MFMA) + in-LDS acts + residual conv.
// Split-bf16 (hi/lo, 3-plane) arithmetic; fast exp2/rcp activations.
// Gated loop triple-buffers W/X (prefetch distance 2, vmcnt(6)) to cover
// L3/HBM latency; occupancy is register-capped (~4 waves/SIMD) so we spend
// LDS on pipeline depth instead.
// Fallback (ws too small): round-1 fp32 VALU path.

#define KC 32

typedef __bf16 bf16_t;
typedef __bf16 bf16x4 __attribute__((ext_vector_type(4)));
typedef __bf16 bf16x8 __attribute__((ext_vector_type(8)));
typedef float f32x16 __attribute__((ext_vector_type(16)));

__device__ __align__(16) __bf16 g_wi_dev[98304];   // w_in split+swizzled
__device__ float g_pooled[4096];                    // [b][256] pooled skip

__device__ __forceinline__ void gl_lds16(const void* g, void* l) {
    __builtin_amdgcn_global_load_lds(
        (const __attribute__((address_space(1))) unsigned int*)g,
        (__attribute__((address_space(3))) unsigned int*)l, 16, 0, 0);
}

__device__ __forceinline__ float fast_sigmoid(float x) {
    float e = __builtin_amdgcn_exp2f(-1.4426950408889634f * x);
    return __builtin_amdgcn_rcpf(1.0f + e);
}
__device__ __forceinline__ float fast_tanh(float x) {
    float e = __builtin_amdgcn_exp2f(-2.8853900817779268f * x);
    return fmaf(2.0f, __builtin_amdgcn_rcpf(1.0f + e), -1.0f);
}

// ---------------- weight prep: split + swizzle ----------------
// chunk layout: [row][slot ps<4][e<8]; content slot s = ps ^ ((row>>1)&3);
// k'' = c*32 + s*8 + e.
__global__ __launch_bounds__(256) void prep_wg_kernel(
    const float* __restrict__ dw, bf16_t* __restrict__ wg)
{
    int idx = blockIdx.x * 256 + threadIdx.x;   // 3,145,728
    int e = idx & 7, ps = (idx >> 3) & 3, row = (idx >> 5) & 255;
    int lc = idx >> 13, c = lc % 24, layer = lc / 24;
    int s = ps ^ ((row >> 1) & 3);
    int k = c * 32 + s * 8 + e;
    int plane = k >> 8, kp = k & 255;
    int tap = kp >> 7, ch = kp & 127;
    float w = dw[(((size_t)layer * 256 + row) * 128 + ch) * 2 + tap];
    bf16_t hb = (bf16_t)w;
    wg[idx] = (plane < 2) ? hb : (bf16_t)(w - (float)hb);
}

__global__ __launch_bounds__(256) void prep_wr_kernel(
    const float* __restrict__ rw, bf16_t* __restrict__ wr)
{
    int idx = blockIdx.x * 256 + threadIdx.x;   // 737,280
    int e = idx & 7, ps = (idx >> 3) & 3, row = (idx >> 5) & 127;
    int lc = idx >> 12, c = lc % 12, layer = lc / 12;
    int s = ps ^ ((row >> 1) & 3);
    int k = c * 32 + s * 8 + e;
    int plane = k >> 7, ch = k & 127;
    float w = rw[((size_t)layer * 128 + row) * 128 + ch];
    bf16_t hb = (bf16_t)w;
    wr[idx] = (plane < 2) ? hb : (bf16_t)(w - (float)hb);
}

__global__ __launch_bounds__(256) void prep_wi_kernel(const float* __restrict__ wi)
{
    int idx = blockIdx.x * 256 + threadIdx.x;   // 98,304
    int e = idx & 7, ps = (idx >> 3) & 3, row = (idx >> 5) & 127;
    int c = idx >> 12;                          // 0..23
    int s = ps ^ ((row >> 1) & 3);
    int k = c * 32 + s * 8 + e;
    int plane = k >> 8, ch = k & 255;
    float w = wi[(size_t)row * 256 + ch];
    bf16_t hb = (bf16_t)w;
    g_wi_dev[idx] = (plane < 2) ? hb : (bf16_t)(w - (float)hb);
}

__global__ __launch_bounds__(256) void zero_misc_kernel(bf16_t* __restrict__ zeros)
{
    int idx = blockIdx.x * 256 + threadIdx.x;   // 32768
    zeros[idx] = (bf16_t)0.0f;
    if (idx < 4096) g_pooled[idx] = 0.0f;
}

// ---------------- input transpose: fp32 [ch][t] -> bf16 hi/lo [t][ch] ----------------
__global__ __launch_bounds__(256) void transpose_in(
    const float* __restrict__ input, bf16_t* __restrict__ th,
    bf16_t* __restrict__ tl, int b_off)
{
    __shared__ float Sl[64][65];
    const int tid = threadIdx.x;
    const int t0 = blockIdx.x * 64, ch0 = blockIdx.y * 64, bz = blockIdx.z;
    const int b = b_off + bz;
#pragma unroll
    for (int it = 0; it < 16; ++it) {
        int idx = it * 256 + tid;
        int t = idx & 63, ch = idx >> 6;
        Sl[ch][t] = input[((size_t)b * 256 + ch0 + ch) * 4096 + t0 + t];
    }
    __syncthreads();
#pragma unroll
    for (int it = 0; it < 16; ++it) {
        int idx = it * 256 + tid;
        int ch = idx & 63, t = idx >> 6;
        float v = Sl[ch][t];
        bf16_t hb = (bf16_t)v;
        size_t o = ((size_t)bz * 4096 + t0 + t) * 256 + ch0 + ch;
        th[o] = hb;
        tl[o] = (bf16_t)(v - (float)hb);
    }
}

// ---------------- fused layer: gated conv + acts + residual conv ----------------
// 512 threads (8 waves). LDS 80KB:
//   gated loop : W tbuf 3x16K [0,48K), X tbuf 3x8K [48K... @49152,73728)
//   epilogue   : acts hi [0,32K), acts lo [32K,64K), resW dbuf [64K,80K)
__global__ __launch_bounds__(512, 4) void fused_layer(
    const bf16_t* __restrict__ xc_hi, const bf16_t* __restrict__ xc_lo,
    bf16_t* __restrict__ xn_hi, bf16_t* __restrict__ xn_lo,
    const bf16_t* __restrict__ zeros,
    const bf16_t* __restrict__ wg_l, const float* __restrict__ dbias,
    const bf16_t* __restrict__ wr_l, const float* __restrict__ rbias,
    float* __restrict__ asum_l, int d, int skipres)
{
    __shared__ __align__(16) char lds[81920];
    const int tid = threadIdx.x;
    const int wave = tid >> 6, lane = tid & 63;
    const int l31 = lane & 31, h = lane >> 5;
    const int wm = wave & 3, wn = wave >> 2;
    const int t0 = blockIdx.x * 128;
    const int b = blockIdx.z;

    f32x16 acc[2][2];
#pragma unroll
    for (int m = 0; m < 2; ++m)
#pragma unroll
        for (int n = 0; n < 2; ++n) acc[m][n] = (f32x16)(0.0f);

    const int t_pos = tid >> 2;
    const int s_x = (tid & 3) ^ ((t_pos >> 1) & 3);
    const int chx = s_x << 3;

    // 3 loads/thread per chunk: 2x W, 1x X
    auto stage_g = [&](int c, int sl) {
        const char* wsrc = (const char*)wg_l + (size_t)c * 16384;
        char* wdst = lds + sl * 16384;
        gl_lds16(wsrc + tid * 16, wdst + tid * 16);
        gl_lds16(wsrc + (tid + 512) * 16, wdst + (tid + 512) * 16);
        int plane = c >> 3;
        int tap = (c >> 2) & 1;
        int ch = ((c & 3) << 5) + chx;
        const bf16_t* src = (plane == 1) ? xc_lo : xc_hi;
        int tg = t0 + t_pos - (tap ? 0 : d);
        const bf16_t* sp = (tg >= 0) ? (src + ((size_t)b * 4096 + tg) * 128 + ch)
                                     : (zeros + ch);
        gl_lds16(sp, lds + 49152 + sl * 8192 + tid * 16);
    };

    stage_g(0, 0);
    stage_g(1, 1);
    const int swz = (l31 >> 1) & 3;
    int aoff[2][2], boff[2][2];
#pragma unroll
    for (int m = 0; m < 2; ++m)
#pragma unroll
        for (int s2 = 0; s2 < 2; ++s2)
            aoff[m][s2] = ((m ? 128 + wm * 32 : wm * 32) + l31) * 64 +
                          (((s2 * 2 + h) ^ swz) << 4);
#pragma unroll
    for (int n = 0; n < 2; ++n)
#pragma unroll
        for (int s2 = 0; s2 < 2; ++s2)
            boff[n][s2] = (wn * 64 + n * 32 + l31) * 64 + (((s2 * 2 + h) ^ swz) << 4);

    for (int c = 0; c < 24; ++c) {
        // prefetch distance 2: chunk c's loads were issued 2 iterations ago
        if (c < 22) {
            int c2 = c + 2;
            stage_g(c2, c2 % 3);
            asm volatile("s_waitcnt vmcnt(6)" ::: "memory");
        } else if (c < 23) {
            asm volatile("s_waitcnt vmcnt(3)" ::: "memory");
        } else {
            asm volatile("s_waitcnt vmcnt(0)" ::: "memory");
        }
        __builtin_amdgcn_s_barrier();    // chunk-c loads landed for all waves

        const char* wb = lds + (c % 3) * 16384;
        const char* xb = lds + 49152 + (c % 3) * 8192;
        bf16x8 a0s[2], a1s[2], b0s[2], b1s[2];
#pragma unroll
        for (int s2 = 0; s2 < 2; ++s2) {
            a0s[s2] = *(const bf16x8*)(wb + aoff[0][s2]);
            a1s[s2] = *(const bf16x8*)(wb + aoff[1][s2]);
            b0s[s2] = *(const bf16x8*)(xb + boff[0][s2]);
            b1s[s2] = *(const bf16x8*)(xb + boff[1][s2]);
        }
        __builtin_amdgcn_s_setprio(1);
#pragma unroll
        for (int s2 = 0; s2 < 2; ++s2) {
            acc[0][0] = __builtin_amdgcn_mfma_f32_32x32x16_bf16(a0s[s2], b0s[s2], acc[0][0], 0, 0, 0);
            acc[0][1] = __builtin_amdgcn_mfma_f32_32x32x16_bf16(a0s[s2], b1s[s2], acc[0][1], 0, 0, 0);
            acc[1][0] = __builtin_amdgcn_mfma_f32_32x32x16_bf16(a1s[s2], b0s[s2], acc[1][0], 0, 0, 0);
            acc[1][1] = __builtin_amdgcn_mfma_f32_32x32x16_bf16(a1s[s2], b1s[s2], acc[1][1], 0, 0, 0);
        }
        __builtin_amdgcn_s_setprio(0);
        __builtin_amdgcn_s_barrier();    // reads of slot c%3 retired -> safe to restage
    }
    __syncthreads();

    // ---- acts epilogue ----
    auto stage_rw = [&](int c, int sl) {
        gl_lds16((const char*)wr_l + (size_t)c * 8192 + tid * 16,
                 lds + 65536 + sl * 8192 + tid * 16);
    };
    if (!skipres) stage_rw(0, 0);   // HBM latency hides under activation VALU

    float psum[16];
#pragma unroll
    for (int u = 0; u < 16; ++u) psum[u] = 0.0f;

#pragma unroll
    for (int n = 0; n < 2; ++n) {
        int t = wn * 64 + n * 32 + l31;
        int sw = (t & 7) << 4;
#pragma unroll
        for (int rg = 0; rg < 4; ++rg) {
            int ch0 = wm * 32 + rg * 8 + 4 * h;
            bf16x4 hv, lv;
#pragma unroll
            for (int j = 0; j < 4; ++j) {
                int r = rg * 4 + j;
                float a1v = acc[0][n][r] + dbias[ch0 + j];
                float a2v = acc[1][n][r] + dbias[128 + ch0 + j];
                float a = fast_tanh(a1v) * fast_sigmoid(a2v);
                psum[rg * 4 + j] += a;
                bf16_t hb = (bf16_t)a;
                hv[j] = hb;
                lv[j] = (bf16_t)(a - (float)hb);
            }
            int low = (ch0 * 2) ^ sw;
            *(bf16x4*)(lds + t * 256 + low) = hv;
            *(bf16x4*)(lds + 32768 + t * 256 + low) = lv;
        }
    }

#pragma unroll
    for (int u = 0; u < 16; ++u) {
        float v = psum[u];
        v += __shfl_xor(v, 1);
        v += __shfl_xor(v, 2);
        v += __shfl_xor(v, 4);
        v += __shfl_xor(v, 8);
        v += __shfl_xor(v, 16);
        psum[u] = v;
    }
    if (l31 == 0) {
#pragma unroll
        for (int u = 0; u < 16; ++u) {
            int ch = wm * 32 + (u >> 2) * 8 + 4 * h + (u & 3);
            atomicAdd(asum_l + b * 128 + ch, psum[u]);
        }
    }
    if (skipres) return;

    asm volatile("s_waitcnt lgkmcnt(0)" ::: "memory");
    __builtin_amdgcn_s_barrier();   // acts visible to all waves (resW c0 in flight)

    // ---- residual K-loop: M=128(x ch) x N=128(t), K''=384, 12 chunks ----
    // wave tile 32ch x 64t: rows wm*32, cols wn*64.
    f32x16 accr[2];
    accr[0] = (f32x16)(0.0f);
    accr[1] = (f32x16)(0.0f);
    int tl_[2], mk_[2];
#pragma unroll
    for (int n = 0; n < 2; ++n) {
        tl_[n] = wn * 64 + n * 32 + l31;
        mk_[n] = (tl_[n] & 7) << 4;
    }

    for (int c = 0; c < 12; ++c) {
        if (c < 11) {
            stage_rw(c + 1, (c + 1) & 1);
            asm volatile("s_waitcnt vmcnt(1)" ::: "memory");
        } else {
            asm volatile("s_waitcnt vmcnt(0)" ::: "memory");
        }
        __builtin_amdgcn_s_barrier();

        const char* ab = lds + 65536 + (c & 1) * 8192;
        int p = c >> 2;
        int cb = (c & 3) << 6;
        const char* bb = lds + (p == 1 ? 32768 : 0);
        bf16x8 av[2], bv[2][2];
#pragma unroll
        for (int s2 = 0; s2 < 2; ++s2) {
            av[s2] = *(const bf16x8*)(ab + (wm * 32 + l31) * 64 +
                                      (((s2 * 2 + h) ^ swz) << 4));
#pragma unroll
            for (int n = 0; n < 2; ++n) {
                int low = (cb + ((s2 * 2 + h) << 4)) ^ mk_[n];
                bv[n][s2] = *(const bf16x8*)(bb + tl_[n] * 256 + low);
            }
        }
        __builtin_amdgcn_s_setprio(1);
#pragma unroll
        for (int s2 = 0; s2 < 2; ++s2) {
            accr[0] = __builtin_amdgcn_mfma_f32_32x32x16_bf16(av[s2], bv[0][s2], accr[0], 0, 0, 0);
            accr[1] = __builtin_amdgcn_mfma_f32_32x32x16_bf16(av[s2], bv[1][s2], accr[1], 0, 0, 0);
        }
        __builtin_amdgcn_s_setprio(0);
        __builtin_amdgcn_s_barrier();
    }

    // ---- residual epilogue: x_new = accr + rbias + x_old(hi+lo) ----
#pragma unroll
    for (int n = 0; n < 2; ++n) {
        int t = tl_[n];
        size_t trow = ((size_t)b * 4096 + t0 + t) * 128;
#pragma unroll
        for (int rg = 0; rg < 4; ++rg) {
            int ch0 = wm * 32 + rg * 8 + 4 * h;
            bf16x4 oh = *(const bf16x4*)(xc_hi + trow + ch0);
            bf16x4 ol = *(const bf16x4*)(xc_lo + trow + ch0);
            bf16x4 nh, nl;
#pragma unroll
            for (int j = 0; j < 4; ++j) {
                float v = accr[n][rg * 4 + j] + rbias[ch0 + j] +
                          (float)oh[j] + (float)ol[j];
                bf16_t hb = (bf16_t)v;
                nh[j] = hb;
                nl[j] = (bf16_t)(v - (float)hb);
            }
            *(bf16x4*)(xn_hi + trow + ch0) = nh;
            *(bf16x4*)(xn_lo + trow + ch0) = nl;
        }
    }
}

// ---------------- input pointwise MFMA (K=256, 3 planes) ----------------
// BM=128, BN=128, 4 waves, wave 64x64. Writes xt [b][4096][128] hi/lo.
__global__ __launch_bounds__(256) void pw_mfma_in(
    const bf16_t* __restrict__ sh, const bf16_t* __restrict__ sl,
    const float* __restrict__ bias,
    bf16_t* __restrict__ xth, bf16_t* __restrict__ xtl, int b_off)
{
    constexpr int NCHUNK = 24;
    __shared__ __align__(16) char lds[32768];
    const int tid = threadIdx.x;
    const int wave = tid >> 6, lane = tid & 63;
    const int l31 = lane & 31, h = lane >> 5;
    const int wm = wave & 1, wn = wave >> 1;
    const int t0 = blockIdx.x * 128;
    const int bz = blockIdx.z;
    const bf16_t* w = (const bf16_t*)g_wi_dev;

    f32x16 acc[2][2];
#pragma unroll
    for (int m = 0; m < 2; ++m)
#pragma unroll
        for (int n = 0; n < 2; ++n) acc[m][n] = (f32x16)(0.0f);

    auto stage = [&](int c, int sl_) {
        const char* wsrc = (const char*)w + (size_t)c * 8192;
        char* wdst = lds + sl_ * 8192;
#pragma unroll
        for (int it = 0; it < 2; ++it) {
            int g = tid + 256 * it;
            gl_lds16(wsrc + g * 16, wdst + g * 16);
        }
        int plane = c / 8;
        int chb = (c % 8) * 32;
        const bf16_t* src = (plane == 1) ? sl : sh;
#pragma unroll
        for (int it = 0; it < 2; ++it) {
            int row = (tid >> 2) + it * 64;
            int ps = tid & 3;
            int s_x = ps ^ ((row >> 1) & 3);
            size_t gi = ((size_t)bz * 4096 + t0 + row) * 256 + chb + s_x * 8;
            gl_lds16(src + gi, lds + 16384 + sl_ * 8192 + (row * 4 + ps) * 16);
        }
    };

    stage(0, 0);
    const int swz = (l31 >> 1) & 3;
    int aoff[2][2], boff[2][2];
#pragma unroll
    for (int m = 0; m < 2; ++m)
#pragma unroll
        for (int s2 = 0; s2 < 2; ++s2)
            aoff[m][s2] = (wm * 64 + m * 32 + l31) * 64 + (((s2 * 2 + h) ^ swz) << 4);
#pragma unroll
    for (int n = 0; n < 2; ++n)
#pragma unroll
        for (int s2 = 0; s2 < 2; ++s2)
            boff[n][s2] = (wn * 64 + n * 32 + l31) * 64 + (((s2 * 2 + h) ^ swz) << 4);

    for (int c = 0; c < NCHUNK; ++c) {
        if (c < NCHUNK - 1) {
            stage(c + 1, (c + 1) & 1);
            asm volatile("s_waitcnt vmcnt(4)" ::: "memory");
        } else {
            asm volatile("s_waitcnt vmcnt(0)" ::: "memory");
        }
        __builtin_amdgcn_s_barrier();

        const char* wb = lds + (c & 1) * 8192;
        const char* xb = lds + 16384 + (c & 1) * 8192;
#pragma unroll
        for (int s2 = 0; s2 < 2; ++s2) {
            bf16x8 a0 = *(const bf16x8*)(wb + aoff[0][s2]);
            bf16x8 a1 = *(const bf16x8*)(wb + aoff[1][s2]);
            bf16x8 b0 = *(const bf16x8*)(xb + boff[0][s2]);
            bf16x8 b1 = *(const bf16x8*)(xb + boff[1][s2]);
            acc[0][0] = __builtin_amdgcn_mfma_f32_32x32x16_bf16(a0, b0, acc[0][0], 0, 0, 0);
            acc[0][1] = __builtin_amdgcn_mfma_f32_32x32x16_bf16(a0, b1, acc[0][1], 0, 0, 0);
            acc[1][0] = __builtin_amdgcn_mfma_f32_32x32x16_bf16(a1, b0, acc[1][0], 0, 0, 0);
            acc[1][1] = __builtin_amdgcn_mfma_f32_32x32x16_bf16(a1, b1, acc[1][1], 0, 0, 0);
        }
        __builtin_amdgcn_s_barrier();
    }

    const int b = b_off + bz;
#pragma unroll
    for (int n = 0; n < 2; ++n) {
        int t = wn * 64 + n * 32 + l31;
        size_t trow = ((size_t)b * 4096 + t0 + t) * 128;
#pragma unroll
        for (int m = 0; m < 2; ++m) {
#pragma unroll
            for (int rg = 0; rg < 4; ++rg) {
                int ch0 = wm * 64 + m * 32 + rg * 8 + 4 * h;
                bf16x4 nh, nl;
#pragma unroll
                for (int j = 0; j < 4; ++j) {
                    float v = acc[m][n][rg * 4 + j] + bias[ch0 + j];
                    bf16_t hb = (bf16_t)v;
                    nh[j] = hb;
                    nl[j] = (bf16_t)(v - (float)hb);
                }
                *(bf16x4*)(xth + trow + ch0) = nh;
                *(bf16x4*)(xtl + trow + ch0) = nl;
            }
        }
    }
}

// ---------------- output head ----------------
__global__ __launch_bounds__(256) void skip_partial(
    const float* __restrict__ asum, const float* __restrict__ skip_w)
{
    const int i = blockIdx.x >> 4, b = blockIdx.x & 15, s = threadIdx.x;
    const float* sw = skip_w + ((size_t)i * 256 + s) * 128;
    const float* as = asum + i * 2048 + b * 128;
    float t = 0.0f;
#pragma unroll 8
    for (int r = 0; r < 128; ++r) t = fmaf(sw[r], as[r], t);
    atomicAdd(&g_pooled[b * 256 + s], t);
}

__global__ __launch_bounds__(256) void head_kernel(
    const float* __restrict__ skip_b, const float* __restrict__ w_out,
    const float* __restrict__ lin_w, const float* __restrict__ lin_b,
    float* __restrict__ out)
{
    const int b = blockIdx.x;
    const int s = threadIdx.x;
    float sb = 0.0f;
#pragma unroll
    for (int i = 0; i < 16; ++i) sb += skip_b[i * 256 + s];
    __shared__ float pl[256];
    pl[s] = g_pooled[b * 256 + s] * (1.0f / 4096.0f) + sb;
    __syncthreads();
    __shared__ float o1[12];
    if (s < 12) {
        float v = 0.0f;
        for (int q = 0; q < 256; ++q) v = fmaf(w_out[s * 256 + q], pl[q], v);
        o1[s] = v;
    }
    __syncthreads();
    if (s < 12) {
        float v = lin_b[s];
#pragma unroll
        for (int m = 0; m < 12; ++m) v = fmaf(lin_w[s * 12 + m], o1[m], v);
        out[b * 12 + s] = v;
    }
}

// ================= fallback fp32 path (round-1, proven) =================
__global__ __launch_bounds__(256) void pw_conv_kernel(
    const float* __restrict__ src, const float* __restrict__ W,
    const float* __restrict__ bias, float* __restrict__ dst,
    int K, int accumulate)
{
    __shared__ float Wl[KC][68];
    __shared__ float Sl[KC][68];
    const int tid = threadIdx.x;
    const int t0 = blockIdx.x * 64;
    const int row0 = blockIdx.y * 64;
    const int b = blockIdx.z;
    const int i4 = (tid >> 4) * 4;
    const int j4 = (tid & 15) * 4;
    float acc[4][4];
#pragma unroll
    for (int r = 0; r < 4; ++r) {
        float bv = bias[row0 + i4 + r];
#pragma unroll
        for (int c = 0; c < 4; ++c) acc[r][c] = bv;
    }
    const float* sb = src + (size_t)b * K * 4096;
    for (int k0 = 0; k0 < K; k0 += KC) {
        __syncthreads();
#pragma unroll
        for (int it = 0; it < 8; ++it) {
            int idx = it * 256 + tid;
            int kk = idx & 31, oo = idx >> 5;
            Wl[kk][oo] = W[(size_t)(row0 + oo) * K + (k0 + kk)];
        }
#pragma unroll
        for (int it = 0; it < 8; ++it) {
            int idx = it * 256 + tid;
            int t = idx & 63, kk = idx >> 6;
            Sl[kk][t] = sb[(size_t)(k0 + kk) * 4096 + t0 + t];
        }
        __syncthreads();
#pragma unroll
        for (int kk = 0; kk < KC; ++kk) {
            float4 wv = *(const float4*)&Wl[kk][i4];
            float4 sv = *(const float4*)&Sl[kk][j4];
            float wr_[4] = {wv.x, wv.y, wv.z, wv.w};
            float sc[4] = {sv.x, sv.y, sv.z, sv.w};
#pragma unroll
            for (int r = 0; r < 4; ++r)
#pragma unroll
                for (int c = 0; c < 4; ++c)
                    acc[r][c] = fmaf(wr_[r], sc[c], acc[r][c]);
        }
    }
    float* db = dst + (size_t)b * 128 * 4096;
#pragma unroll
    for (int r = 0; r < 4; ++r) {
        float* p = db + (size_t)(row0 + i4 + r) * 4096 + t0 + j4;
        float4 v;
        if (accumulate) {
            float4 old = *(const float4*)p;
            v.x = acc[r][0] + old.x; v.y = acc[r][1] + old.y;
            v.z = acc[r][2] + old.z; v.w = acc[r][3] + old.w;
        } else {
            v.x = acc[r][0]; v.y = acc[r][1]; v.z = acc[r][2]; v.w = acc[r][3];
        }
        *(float4*)p = v;
    }
}

__global__ __launch_bounds__(256) void gated_conv_kernel(
    const float* __restrict__ x, const float* __restrict__ Wd,
    const float* __restrict__ dbias, float* __restrict__ acts, int d)
{
    __shared__ float Wt0[KC][68], Wt1[KC][68], Ws0[KC][68], Ws1[KC][68];
    __shared__ float Sc[KC][68], Sp[KC][68];
    const int tid = threadIdx.x;
    const int t0 = blockIdx.x * 64;
    const int row0 = blockIdx.y * 64;
    const int b = blockIdx.z;
    const int i4 = (tid >> 4) * 4;
    const int j4 = (tid & 15) * 4;
    float a1[4][4], a2[4][4];
#pragma unroll
    for (int r = 0; r < 4; ++r) {
        float bt = dbias[row0 + i4 + r];
        float bs = dbias[128 + row0 + i4 + r];
#pragma unroll
        for (int c = 0; c < 4; ++c) { a1[r][c] = bt; a2[r][c] = bs; }
    }
    const float* xb = x + (size_t)b * 128 * 4096;
    for (int k0 = 0; k0 < 128; k0 += KC) {
        __syncthreads();
#pragma unroll
        for (int it = 0; it < 8; ++it) {
            int idx = it * 256 + tid;
            int kk = idx & 31, oo = idx >> 5;
            float2 wt = *(const float2*)(Wd + ((size_t)(row0 + oo) * 128 + (k0 + kk)) * 2);
            float2 ws = *(const float2*)(Wd + ((size_t)(128 + row0 + oo) * 128 + (k0 + kk)) * 2);
            Wt0[kk][oo] = wt.x; Wt1[kk][oo] = wt.y;
            Ws0[kk][oo] = ws.x; Ws1[kk][oo] = ws.y;
        }
#pragma unroll
        for (int it = 0; it < 8; ++it) {
            int idx = it * 256 + tid;
            int t = idx & 63, kk = idx >> 6;
            Sc[kk][t] = xb[(size_t)(k0 + kk) * 4096 + t0 + t];
            int gt = t0 + t - d;
            Sp[kk][t] = (gt >= 0) ? xb[(size_t)(k0 + kk) * 4096 + gt] : 0.0f;
        }
        __syncthreads();
#pragma unroll
        for (int kk = 0; kk < KC; ++kk) {
            float4 xcv4 = *(const float4*)&Sc[kk][j4];
            float4 xpv4 = *(const float4*)&Sp[kk][j4];
            float4 wt0 = *(const float4*)&Wt0[kk][i4];
            float4 wt1 = *(const float4*)&Wt1[kk][i4];
            float4 ws0 = *(const float4*)&Ws0[kk][i4];
            float4 ws1 = *(const float4*)&Ws1[kk][i4];
            float xc[4] = {xcv4.x, xcv4.y, xcv4.z, xcv4.w};
            float xp[4] = {xpv4.x, xpv4.y, xpv4.z, xpv4.w};
            float t0r[4] = {wt0.x, wt0.y, wt0.z, wt0.w};
            float t1r[4] = {wt1.x, wt1.y, wt1.z, wt1.w};
            float s0r[4] = {ws0.x, ws0.y, ws0.z, ws0.w};
            float s1r[4] = {ws1.x, ws1.y, ws1.z, ws1.w};
#pragma unroll
            for (int r = 0; r < 4; ++r)
#pragma unroll
                for (int c = 0; c < 4; ++c) {
                    a1[r][c] = fmaf(t0r[r], xp[c], a1[r][c]);
                    a1[r][c] = fmaf(t1r[r], xc[c], a1[r][c]);
                    a2[r][c] = fmaf(s0r[r], xp[c], a2[r][c]);
                    a2[r][c] = fmaf(s1r[r], xc[c], a2[r][c]);
                }
        }
    }
    float* ab = acts + (size_t)b * 128 * 4096;
#pragma unroll
    for (int r = 0; r < 4; ++r) {
        float4 v;
#pragma unroll
        for (int c = 0; c < 4; ++c) {
            float th = tanhf(a1[r][c]);
            float sg = 1.0f / (1.0f + expf(-a2[r][c]));
            ((float*)&v)[c] = th * sg;
        }
        *(float4*)&ab[(size_t)(row0 + i4 + r) * 4096 + t0 + j4] = v;
    }
}

__global__ __launch_bounds__(256) void actsum_kernel(
    const float* __restrict__ acts, float* __restrict__ out)
{
    const int br = blockIdx.x;
    const float* p = acts + (size_t)br * 4096;
    float s = 0.0f;
#pragma unroll
    for (int c = 0; c < 16; ++c) s += p[c * 256 + threadIdx.x];
    __shared__ float red[256];
    red[threadIdx.x] = s;
    __syncthreads();
    for (int off = 128; off > 0; off >>= 1) {
        if (threadIdx.x < off) red[threadIdx.x] += red[threadIdx.x + off];
        __syncthreads();
    }
    if (threadIdx.x == 0) out[br] = red[0];
}

__global__ __launch_bounds__(256) void final_kernel(
    const float* __restrict__ actsum, const float* __restrict__ skip_w,
    const float* __restrict__ skip_b, const float* __restrict__ w_out,
    const float* __restrict__ lin_w, const float* __restrict__ lin_b,
    float* __restrict__ out)
{
    const int b = blockIdx.x;
    const int s = threadIdx.x;
    float acc = 0.0f;
    for (int i = 0; i < 16; ++i) {
        const float* sw = skip_w + ((size_t)i * 256 + s) * 128;
        const float* as = actsum + ((size_t)i * 16 + b) * 128;
        float t = 0.0f;
#pragma unroll 8
        for (int r = 0; r < 128; ++r) t = fmaf(sw[r], as[r], t);
        acc += t;
    }
    float sb = 0.0f;
    for (int i = 0; i < 16; ++i) sb += skip_b[i * 256 + s];
    __shared__ float pl[256];
    pl[s] = acc * (1.0f / 4096.0f) + sb;
    __syncthreads();
    __shared__ float o1[12];
    if (s < 12) {
        float v = 0.0f;
        for (int qq = 0; qq < 256; ++qq) v = fmaf(w_out[s * 256 + qq], pl[qq], v);
        o1[s] = v;
    }
    __syncthreads();
    if (s < 12) {
        float v = lin_b[s];
#pragma unroll
        for (int m = 0; m < 12; ++m) v = fmaf(lin_w[s * 12 + m], o1[m], v);
        out[b * 12 + s] = v;
    }
}

// =======================================================================
extern "C" void kernel_launch(void* const* d_in, const int* in_sizes, int n_in,
                              void* d_out, int out_size, void* d_ws, size_t ws_size,
                              hipStream_t stream)
{
    const float* input    = (const float*)d_in[0];
    const float* w_in     = (const float*)d_in[1];
    const float* b_in     = (const float*)d_in[2];
    const float* dilate_w = (const float*)d_in[3];
    const float* dilate_b = (const float*)d_in[4];
    const float* res_w    = (const float*)d_in[5];
    const float* res_b    = (const float*)d_in[6];
    const float* skip_w   = (const float*)d_in[7];
    const float* skip_b   = (const float*)d_in[8];
    const float* w_out    = (const float*)d_in[9];
    const float* lin_w    = (const float*)d_in[10];
    const float* lin_b    = (const float*)d_in[11];
    float* out = (float*)d_out;

    const size_t NEED = 77103104ULL;
    if (ws_size >= NEED) {
        char* base = (char*)d_ws;
        bf16_t* xtA_hi = (bf16_t*)(base);                 // 16,777,216 B
        bf16_t* xtA_lo = (bf16_t*)(base + 16777216);      // 16,777,216 B
        bf16_t* xtB_hi = (bf16_t*)(base + 33554432);      // 16,777,216 B
        bf16_t* xtB_lo = (bf16_t*)(base + 50331648);      // 16,777,216 B
        bf16_t* wg     = (bf16_t*)(base + 67108864);      //  6,291,456 B
        bf16_t* wr     = (bf16_t*)(base + 73400320);      //  1,474,560 B
        float*  asum   = (float*)(base + 74874880);       //    131,072 B
        bf16_t* zeros  = (bf16_t*)(base + 75005952);      //     65,536 B

        hipMemsetAsync(asum, 0, 131072, stream);
        zero_misc_kernel<<<dim3(128), dim3(256), 0, stream>>>(zeros);
        prep_wg_kernel<<<dim3(12288), dim3(256), 0, stream>>>(dilate_w, wg);
        prep_wr_kernel<<<dim3(2880), dim3(256), 0, stream>>>(res_w, wr);
        prep_wi_kernel<<<dim3(384), dim3(256), 0, stream>>>(w_in);

        // input conv in two 8-batch passes; xtB buffers as transpose scratch
        for (int pass = 0; pass < 2; ++pass) {
            transpose_in<<<dim3(64, 4, 8), dim3(256), 0, stream>>>(
                input, xtB_hi, xtB_lo, pass * 8);
            pw_mfma_in<<<dim3(32, 1, 8), dim3(256), 0, stream>>>(
                xtB_hi, xtB_lo, b_in, xtA_hi, xtA_lo, pass * 8);
        }

        for (int i = 0; i < 16; ++i) {
            int d = 1 << (i % 9);
            const bf16_t* xc_hi = (i & 1) ? xtB_hi : xtA_hi;
            const bf16_t* xc_lo = (i & 1) ? xtB_lo : xtA_lo;
            bf16_t* xn_hi = (i & 1) ? xtA_hi : xtB_hi;
            bf16_t* xn_lo = (i & 1) ? xtA_lo : xtB_lo;
            int skipres = (i == 15) ? 1 : 0;
            fused_layer<<<dim3(32, 1, 16), dim3(512), 0, stream>>>(
                xc_hi, xc_lo, xn_hi, xn_lo, zeros,
                wg + (size_t)i * 196608, dilate_b + i * 256,
                wr + (size_t)(skipres ? 0 : i) * 49152,
                res_b + (skipres ? 0 : i) * 128,
                asum + i * 2048, d, skipres);
        }
        skip_partial<<<dim3(256), dim3(256), 0, stream>>>(asum, skip_w);
        head_kernel<<<dim3(16), dim3(256), 0, stream>>>(
            skip_b, w_out, lin_w, lin_b, out);
    } else {
        // fallback: fp32 VALU path (round 1)
        float* ws   = (float*)d_ws;
        float* x    = ws;
        float* acts = ws + 8388608;
        float* asum = ws + 16777216;
        dim3 grid(64, 2, 16), blk(256, 1, 1);
        pw_conv_kernel<<<grid, blk, 0, stream>>>(input, w_in, b_in, x, 256, 0);
        for (int i = 0; i < 16; ++i) {
            int d = 1 << (i % 9);
            gated_conv_kernel<<<grid, blk, 0, stream>>>(
                x, dilate_w + (size_t)i * 256 * 128 * 2, dilate_b + i * 256, acts, d);
            actsum_kernel<<<dim3(2048), blk, 0, stream>>>(acts, asum + i * 2048);
            if (i < 15) {
                pw_conv_kernel<<<grid, blk, 0, stream>>>(
                    acts, res_w + (size_t)i * 128 * 128, res_b + i * 128, x, 128, 1);
            }
        }
        final_kernel<<<dim3(16), blk, 0, stream>>>(
            asum, skip_w, skip_b, w_out, lin_w, lin_b, out);
    }
}